// Round 1
// 319.752 us; speedup vs baseline: 1.0432x; 1.0432x over previous
//
#include <hip/hip_runtime.h>
#include <hip/hip_bf16.h>
#include <math.h>

#define BB 8
#define SS 2048
#define DD 1024
#define HH 16
#define DHH 64
#define NROWS (BB*SS)   // 16384
#define QSLICE ((size_t)BB * HH * SS)   // elems per qscore K-split slice

typedef unsigned short u16;
typedef __attribute__((ext_vector_type(8))) __bf16 bf16x8;
typedef __attribute__((ext_vector_type(4))) float f32x4;

__device__ __forceinline__ u16 f2bf(float f) {
    union { float f; unsigned u; } v; v.f = f;
    unsigned r = v.u + 0x7fffu + ((v.u >> 16) & 1u);
    return (u16)(r >> 16);
}
__device__ __forceinline__ float bf2f(u16 b) {
    union { unsigned u; float f; } v; v.u = ((unsigned)b) << 16;
    return v.f;
}

__device__ __forceinline__ void load_lds16(const void* g, void* l) {
    __builtin_amdgcn_global_load_lds(
        (const __attribute__((address_space(1))) unsigned int*)g,
        (__attribute__((address_space(3))) unsigned int*)l,
        16, 0, 0);
}

// raw workgroup barrier WITHOUT the vmcnt(0)/lgkmcnt(0) drain __syncthreads forces.
// asm memory clobbers on both sides pin compiler-visible memory ops (ds_read / load_lds)
// to their side of the barrier.
#define BAR() do { asm volatile("" ::: "memory"); \
                   __builtin_amdgcn_s_barrier();  \
                   asm volatile("" ::: "memory"); } while (0)

// ---------------- cast hs fp32 -> bf16 ----------------
__global__ __launch_bounds__(256) void cast_bf16_kernel(const float* __restrict__ in,
                                                        u16* __restrict__ out, int n4) {
    int i = blockIdx.x * 256 + threadIdx.x;
    if (i >= n4) return;
    float4 v = ((const float4*)in)[i];
    ushort4 o;
    o.x = f2bf(v.x); o.y = f2bf(v.y); o.z = f2bf(v.z); o.w = f2bf(v.w);
    ((ushort4*)out)[i] = o;
}

// ---------------- W [K,M] fp32 -> WT [M,K] bf16 ----------------
__global__ __launch_bounds__(256) void transpose_cast_kernel(const float* __restrict__ W,
                                                             u16* __restrict__ WT) {
    __shared__ float tile[32][33];
    int m0 = blockIdx.x * 32, k0 = blockIdx.y * 32;
    int tx = threadIdx.x & 31, ty = threadIdx.x >> 5;
    #pragma unroll
    for (int i = 0; i < 4; i++) {
        int kk = ty + i * 8;
        tile[kk][tx] = W[(k0 + kk) * DD + m0 + tx];
    }
    __syncthreads();
    #pragma unroll
    for (int i = 0; i < 4; i++) {
        int mm = ty + i * 8;
        WT[(m0 + mm) * DD + k0 + tx] = f2bf(tile[tx][mm]);
    }
}

// ---------------- Wqa [1024][16] fp32 -> WqaT [16][1024] bf16 ----------------
__global__ __launch_bounds__(256) void wqa_transpose_kernel(const float* __restrict__ Wqa,
                                                            u16* __restrict__ WqaT) {
    int i = blockIdx.x * 256 + threadIdx.x;
    int h = i >> 10, k = i & 1023;
    WqaT[i] = f2bf(Wqa[k * HH + h]);
}

// ---------------- bf16 MFMA GEMM, 256x256 tile, BK=64, double-buffered LDS ----------------
// C[N,1024] = A[N,1024] @ BT^T + bias
// MODE 1: write bf16 to Cb | MODE 2: write fp32 Cf = v + bf2f(res)
// 8 waves (2M x 4N), per-wave 128x64 output, acc[8][4].
// LDS: 2 K-tile buffers (A 32KB + B 32KB each) = 128KB -> 1 block/CU.
// Pipeline: compute buf[cur] | barrier | STAGE(buf[cur], kt+2) | vmcnt(8) waits ONLY
// the previous tile's loads (new 8 stay in flight across the barrier) | barrier.
// XOR swizzle: 16B chunk c of row r stored at chunk-position c ^ (r & 7)
// -> fragment ds_read_b128 is exact 2-way (free); same involution on stage + read.
template<int MODE>
__global__ __launch_bounds__(512, 2)
void gemm256_kernel(const u16* __restrict__ A, const u16* __restrict__ BT,
                    const float* __restrict__ bias, const u16* __restrict__ res,
                    float* __restrict__ Cf, u16* __restrict__ Cb) {
    __shared__ u16 sA[2][256 * 64];
    __shared__ u16 sB[2][256 * 64];
    const int row0 = blockIdx.x * 256;
    const int col0 = blockIdx.y * 256;
    const int t = threadIdx.x;
    const int w = t >> 6, lane = t & 63;
    const int wm = w >> 2, wn = w & 3;          // 2 x 4 wave grid
    const int m16 = lane & 15, quad = lane >> 4;

    f32x4 acc[8][4];
    #pragma unroll
    for (int i = 0; i < 8; i++)
        #pragma unroll
        for (int j = 0; j < 4; j++)
            acc[i][j] = (f32x4){0.f, 0.f, 0.f, 0.f};

    // staging: thread t owns LDS rows (j*64 + t>>3), chunk-position t&7.
    // That position must hold global chunk (t&7) ^ ((t>>3)&7).
    const int srow = t >> 3;                     // 0..63
    const int scol = ((t & 7) ^ (srow & 7)) * 8;
    const u16* Ag = A + (size_t)(row0 + srow) * DD + scol;
    const u16* Bg = BT + (size_t)(col0 + srow) * DD + scol;

    // 8 global_load_lds (4 A + 4 B) per thread per K-tile; wave-contiguous dest:
    // byte offset = w*1024 + lane*16 within each j-block of 8KB.
    auto STAGE = [&](int buf, int k0) {
        #pragma unroll
        for (int j = 0; j < 4; ++j) {
            load_lds16(Ag + k0 + (size_t)j * 64 * DD, &sA[buf][j * 4096 + t * 8]);
            load_lds16(Bg + k0 + (size_t)j * 64 * DD, &sB[buf][j * 4096 + t * 8]);
        }
    };

    // prologue: fill buf0 (kt0), launch buf1 (kt1); wait only buf0's 8 loads.
    STAGE(0, 0);
    STAGE(1, 64);
    asm volatile("s_waitcnt vmcnt(8)" ::: "memory");
    BAR();

    for (int kt = 0; kt < 16; ++kt) {
        const int cur = kt & 1;
        const u16* sAc = sA[cur];
        const u16* sBc = sB[cur];
        #pragma unroll
        for (int ks = 0; ks < 2; ++ks) {
            const int cpos = ((ks * 4 + quad) ^ (m16 & 7)) * 8;
            bf16x8 af[8], bfr[4];
            #pragma unroll
            for (int mi = 0; mi < 8; ++mi)
                af[mi] = *(const bf16x8*)&sAc[(wm * 128 + mi * 16 + m16) * 64 + cpos];
            #pragma unroll
            for (int ni = 0; ni < 4; ++ni)
                bfr[ni] = *(const bf16x8*)&sBc[(wn * 64 + ni * 16 + m16) * 64 + cpos];
            #pragma unroll
            for (int mi = 0; mi < 8; ++mi)
                #pragma unroll
                for (int ni = 0; ni < 4; ++ni)
                    acc[mi][ni] = __builtin_amdgcn_mfma_f32_16x16x32_bf16(
                        af[mi], bfr[ni], acc[mi][ni], 0, 0, 0);
        }
        BAR();                                   // all waves done reading buf[cur]
        if (kt < 14) {
            STAGE(cur, (kt + 2) * 64);           // refill freed buffer
            asm volatile("s_waitcnt vmcnt(8)" ::: "memory");  // prev tile landed
        } else {
            asm volatile("s_waitcnt vmcnt(0)" ::: "memory");  // tail drain
        }
        BAR();                                   // publish landed loads to all waves
    }

    #pragma unroll
    for (int mi = 0; mi < 8; ++mi) {
        #pragma unroll
        for (int r = 0; r < 4; ++r) {
            int row = row0 + wm * 128 + mi * 16 + quad * 4 + r;
            #pragma unroll
            for (int ni = 0; ni < 4; ++ni) {
                int col = col0 + wn * 64 + ni * 16 + m16;
                float v = acc[mi][ni][r] + bias[col];
                size_t idx = (size_t)row * DD + col;
                if (MODE == 1) Cb[idx] = f2bf(v);
                else Cf[idx] = v + bf2f(res[idx]);
            }
        }
    }
}

// ---------------- raw qscore via MFMA, K-split 4 -> separate slices ----------------
// grid = (NROWS/64, 4). qraw[split][b][h][s] = sum_{k in split} q[s][k]*Wqa[k][h]
__global__ __launch_bounds__(256)
void qscore_mfma_kernel(const u16* __restrict__ qbf, const u16* __restrict__ WqaT,
                        float* __restrict__ qraw) {
    int w = threadIdx.x >> 6, lane = threadIdx.x & 63;
    int row0 = blockIdx.x * 64 + w * 16;
    int kbase = blockIdx.y * 256;
    int m16 = lane & 15, quad = lane >> 4;
    f32x4 acc = (f32x4){0.f, 0.f, 0.f, 0.f};
    const u16* ap = qbf + (size_t)(row0 + m16) * DD + kbase + quad * 8;
    const u16* bp = WqaT + (size_t)m16 * DD + kbase + quad * 8;
    #pragma unroll
    for (int kk = 0; kk < 256; kk += 32) {
        bf16x8 a = *(const bf16x8*)(ap + kk);
        bf16x8 b = *(const bf16x8*)(bp + kk);
        acc = __builtin_amdgcn_mfma_f32_16x16x32_bf16(a, b, acc, 0, 0, 0);
    }
    #pragma unroll
    for (int r = 0; r < 4; r++) {
        int grow = row0 + quad * 4 + r;
        int b = grow >> 11, sidx = grow & 2047;
        qraw[((size_t)(blockIdx.y * BB + b) * HH + m16) * SS + sidx] = acc[r];
    }
}

// ---------------- softmax over S, writes slice 0 ----------------
// EPI: x = sum of 4 K-split slices, then (x+bqa[h])*scale+mask
template<bool EPI>
__global__ __launch_bounds__(256)
void softmax_kernel(float* __restrict__ score, const float* __restrict__ bqa,
                    const float* __restrict__ mask) {
    int bh = blockIdx.x;
    int b = bh >> 4, h = bh & 15;
    float* srow = score + ((size_t)bh << 11);
    __shared__ float rm[4], rs[4];
    int t = threadIdx.x;

    float v[8];
    float m = -1e30f;
    #pragma unroll
    for (int i = 0; i < 8; i++) {
        int off = t + i * 256;
        float x;
        if (EPI) {
            x = srow[off] + srow[off + QSLICE] + srow[off + 2 * QSLICE] + srow[off + 3 * QSLICE];
            x = (x + bqa[h]) * 0.125f + mask[b * SS + off];
        } else {
            x = srow[off];
        }
        v[i] = x; m = fmaxf(m, x);
    }
    #pragma unroll
    for (int off = 32; off; off >>= 1) m = fmaxf(m, __shfl_xor(m, off));
    if ((t & 63) == 0) rm[t >> 6] = m;
    __syncthreads();
    m = fmaxf(fmaxf(rm[0], rm[1]), fmaxf(rm[2], rm[3]));

    float sum = 0.f;
    #pragma unroll
    for (int i = 0; i < 8; i++) { v[i] = __expf(v[i] - m); sum += v[i]; }
    #pragma unroll
    for (int off = 32; off; off >>= 1) sum += __shfl_xor(sum, off);
    if ((t & 63) == 0) rs[t >> 6] = sum;
    __syncthreads();
    float inv = 1.0f / (rs[0] + rs[1] + rs[2] + rs[3]);
    #pragma unroll
    for (int i = 0; i < 8; i++) srow[t + i * 256] = v[i] * inv;
}

// ---------------- pooled[b,:,:] += sum_{s in 32-chunk} w[b,h,s] * X[b,s,:] ----------------
// grid = (BB, SS/32). Full 2KB rows read coalesced; lane owns (h=lane>>2, 16 dims).
__global__ __launch_bounds__(256)
void pool_kernel(const float* __restrict__ w, const u16* __restrict__ X,
                 float* __restrict__ pooled) {
    int b = blockIdx.x;
    int s0 = blockIdx.y * 32;
    int t = threadIdx.x;
    int wid = t >> 6, lane = t & 63;
    int h = lane >> 2;
    __shared__ float sw[16 * 33];
    __shared__ float pr[4][64 * 17];
    {
        int hh = t >> 4, si = t & 15;
        const float* wr = w + ((size_t)(b * HH + hh) << 11) + s0;
        sw[hh * 33 + si] = wr[si];
        sw[hh * 33 + si + 16] = wr[si + 16];
    }
    __syncthreads();
    float acc[16];
    #pragma unroll
    for (int j = 0; j < 16; j++) acc[j] = 0.f;
    const u16* xbase = X + ((size_t)(b * SS + s0 + wid * 8) << 10) + lane * 16;
    #pragma unroll
    for (int rr = 0; rr < 8; rr++) {
        float ws = sw[h * 33 + wid * 8 + rr];
        const uint4* xp = (const uint4*)(xbase + (size_t)rr * DD);
        uint4 x0 = xp[0], x1 = xp[1];
        unsigned xw[8] = {x0.x, x0.y, x0.z, x0.w, x1.x, x1.y, x1.z, x1.w};
        #pragma unroll
        for (int i2 = 0; i2 < 8; i2++) {
            union { unsigned u; float f; } lo, hi;
            lo.u = xw[i2] << 16; hi.u = xw[i2] & 0xffff0000u;
            acc[2 * i2]     += ws * lo.f;
            acc[2 * i2 + 1] += ws * hi.f;
        }
    }
    #pragma unroll
    for (int j = 0; j < 16; j++) pr[wid][lane * 17 + j] = acc[j];
    __syncthreads();
    #pragma unroll
    for (int i = 0; i < 4; i++) {
        int idx = t + i * 256;                       // 0..1023 = lane'*16 + j
        int l2 = idx >> 4, j2 = idx & 15;
        float v = pr[0][l2 * 17 + j2] + pr[1][l2 * 17 + j2] +
                  pr[2][l2 * 17 + j2] + pr[3][l2 * 17 + j2];
        int od = (l2 >> 2) * 64 + (l2 & 3) * 16 + j2;  // h*64 + d
        atomicAdd(&pooled[b * DD + od], v);
    }
}

// ---------------- qk_score[b,h,s] = (k[b,s,h*64:]·pq[b,h,:])*scale + mask ----------------
__global__ __launch_bounds__(256)
void qkscore_kernel(const u16* __restrict__ kbf, const float* __restrict__ pq,
                    const float* __restrict__ mask, float* __restrict__ qkscore) {
    int row = blockIdx.x * 4 + (threadIdx.x >> 6);
    int lane = threadIdx.x & 63;
    int b = row >> 11, s = row & 2047;
    int h = lane >> 2, dp = lane & 3;
    const u16* kp = kbf + (size_t)row * DD + h * 64 + dp * 16;
    const float* pqp = pq + (size_t)(b * HH + h) * 64 + dp * 16;
    const uint4* kp4 = (const uint4*)kp;
    uint4 ka = kp4[0], kb4 = kp4[1];
    unsigned kw[8] = {ka.x, ka.y, ka.z, ka.w, kb4.x, kb4.y, kb4.z, kb4.w};
    float acc = 0.f;
    #pragma unroll
    for (int i = 0; i < 8; i++) {
        union { unsigned u; float f; } lo, hi;
        lo.u = kw[i] << 16;
        hi.u = kw[i] & 0xffff0000u;
        acc += lo.f * pqp[2 * i] + hi.f * pqp[2 * i + 1];
    }
    acc += __shfl_xor(acc, 1);
    acc += __shfl_xor(acc, 2);
    if (dp == 0) qkscore[(size_t)(b * HH + h) * SS + s] = acc * 0.125f + mask[b * SS + s];
}

// ---------------- weighted_bf[b,s,h*64+d] = bf16(pk[b,h,d]*q_bf[b,s,h*64+d]) ----------------
__global__ __launch_bounds__(256)
void weighted_kernel(const u16* __restrict__ qbf, const float* __restrict__ pk,
                     u16* __restrict__ wout) {
    int i = blockIdx.x * 256 + threadIdx.x;
    int row = i >> 8;
    int c0 = (i & 255) << 2;
    int b = row >> 11;
    int h = c0 >> 6, d = c0 & 63;
    ushort4 qv = ((const ushort4*)qbf)[i];
    const float4 pv = *(const float4*)(pk + (size_t)(b * HH + h) * 64 + d);
    ushort4 o;
    o.x = f2bf(bf2f(qv.x) * pv.x); o.y = f2bf(bf2f(qv.y) * pv.y);
    o.z = f2bf(bf2f(qv.z) * pv.z); o.w = f2bf(bf2f(qv.w) * pv.w);
    ((ushort4*)wout)[i] = o;
}

extern "C" void kernel_launch(void* const* d_in, const int* in_sizes, int n_in,
                              void* d_out, int out_size, void* d_ws, size_t ws_size,
                              hipStream_t stream) {
    const float* hs   = (const float*)d_in[0];
    const float* mask = (const float*)d_in[1];
    const float* Wq   = (const float*)d_in[2];
    const float* bq   = (const float*)d_in[3];
    const float* Wqa  = (const float*)d_in[4];
    const float* bqa  = (const float*)d_in[5];
    const float* Wk   = (const float*)d_in[6];
    const float* bk   = (const float*)d_in[7];
    const float* Wt   = (const float*)d_in[8];
    const float* bt   = (const float*)d_in[9];
    float* out = (float*)d_out;

    char* ws = (char*)d_ws;
    u16*   hs_bf = (u16*)ws;   ws += (size_t)NROWS * DD * 2;
    u16*   WqT   = (u16*)ws;   ws += (size_t)DD * DD * 2;
    u16*   WkT   = (u16*)ws;   ws += (size_t)DD * DD * 2;
    u16*   WtT   = (u16*)ws;   ws += (size_t)DD * DD * 2;
    u16*   WqaT  = (u16*)ws;   ws += (size_t)HH * DD * 2;
    u16*   q_bf  = (u16*)ws;   ws += (size_t)NROWS * DD * 2;
    u16*   k_bf  = (u16*)ws;   ws += (size_t)NROWS * DD * 2;
    float* qraw  = (float*)ws; ws += QSLICE * 4 * 4;   // 4 K-split slices
    float* qksc  = (float*)ws; ws += (size_t)BB * HH * SS * 4;
    float* pq    = (float*)ws; ws += (size_t)BB * HH * 64 * 4;
    float* pk    = (float*)ws; ws += (size_t)BB * HH * 64 * 4;
    u16*   wbf   = hs_bf;  // alias: hs_bf dead after gemm k, wbf written after

    int n4 = NROWS * DD / 4;
    cast_bf16_kernel<<<n4 / 256, 256, 0, stream>>>(hs, hs_bf, n4);
    transpose_cast_kernel<<<dim3(32, 32), 256, 0, stream>>>(Wq, WqT);
    transpose_cast_kernel<<<dim3(32, 32), 256, 0, stream>>>(Wk, WkT);
    transpose_cast_kernel<<<dim3(32, 32), 256, 0, stream>>>(Wt, WtT);
    wqa_transpose_kernel<<<HH * DD / 256, 256, 0, stream>>>(Wqa, WqaT);

    hipMemsetAsync(pq, 0, (size_t)BB * HH * 64 * 4, stream);
    hipMemsetAsync(pk, 0, (size_t)BB * HH * 64 * 4, stream);

    gemm256_kernel<1><<<dim3(NROWS / 256, DD / 256), 512, 0, stream>>>(hs_bf, WqT, bq, nullptr, nullptr, q_bf);
    gemm256_kernel<1><<<dim3(NROWS / 256, DD / 256), 512, 0, stream>>>(hs_bf, WkT, bk, nullptr, nullptr, k_bf);

    qscore_mfma_kernel<<<dim3(NROWS / 64, 4), 256, 0, stream>>>(q_bf, WqaT, qraw);
    softmax_kernel<true><<<BB * HH, 256, 0, stream>>>(qraw, bqa, mask);
    pool_kernel<<<dim3(BB, SS / 32), 256, 0, stream>>>(qraw, q_bf, pq);
    qkscore_kernel<<<NROWS / 4, 256, 0, stream>>>(k_bf, pq, mask, qksc);
    softmax_kernel<false><<<BB * HH, 256, 0, stream>>>(qksc, nullptr, nullptr);
    pool_kernel<<<dim3(BB, SS / 32), 256, 0, stream>>>(qksc, k_bf, pk);
    weighted_kernel<<<n4 / 256, 256, 0, stream>>>(q_bf, pk, wbf);

    gemm256_kernel<2><<<dim3(NROWS / 256, DD / 256), 512, 0, stream>>>(wbf, WtT, bt, q_bf, out, nullptr);
}

// Round 2
// 313.004 us; speedup vs baseline: 1.0657x; 1.0216x over previous
//
#include <hip/hip_runtime.h>
#include <hip/hip_bf16.h>
#include <math.h>

#define BB 8
#define SS 2048
#define DD 1024
#define HH 16
#define DHH 64
#define NROWS (BB*SS)   // 16384
#define QSLICE ((size_t)BB * HH * SS)   // elems per qscore K-split slice

typedef unsigned short u16;
typedef __attribute__((ext_vector_type(8))) __bf16 bf16x8;
typedef __attribute__((ext_vector_type(4))) float f32x4;

__device__ __forceinline__ u16 f2bf(float f) {
    union { float f; unsigned u; } v; v.f = f;
    unsigned r = v.u + 0x7fffu + ((v.u >> 16) & 1u);
    return (u16)(r >> 16);
}
__device__ __forceinline__ float bf2f(u16 b) {
    union { unsigned u; float f; } v; v.u = ((unsigned)b) << 16;
    return v.f;
}

__device__ __forceinline__ void load_lds16(const void* g, void* l) {
    __builtin_amdgcn_global_load_lds(
        (const __attribute__((address_space(1))) unsigned int*)g,
        (__attribute__((address_space(3))) unsigned int*)l,
        16, 0, 0);
}

// raw workgroup barrier WITHOUT the vmcnt(0)/lgkmcnt(0) drain __syncthreads forces.
#define BAR() do { asm volatile("" ::: "memory"); \
                   __builtin_amdgcn_s_barrier();  \
                   asm volatile("" ::: "memory"); } while (0)

// ---------------- cast hs fp32 -> bf16 ----------------
__global__ __launch_bounds__(256) void cast_bf16_kernel(const float* __restrict__ in,
                                                        u16* __restrict__ out, int n4) {
    int i = blockIdx.x * 256 + threadIdx.x;
    if (i >= n4) return;
    float4 v = ((const float4*)in)[i];
    ushort4 o;
    o.x = f2bf(v.x); o.y = f2bf(v.y); o.z = f2bf(v.z); o.w = f2bf(v.w);
    ((ushort4*)out)[i] = o;
}

// ---------------- W [K,M] fp32 -> WT [M,K] bf16 ----------------
__global__ __launch_bounds__(256) void transpose_cast_kernel(const float* __restrict__ W,
                                                             u16* __restrict__ WT) {
    __shared__ float tile[32][33];
    int m0 = blockIdx.x * 32, k0 = blockIdx.y * 32;
    int tx = threadIdx.x & 31, ty = threadIdx.x >> 5;
    #pragma unroll
    for (int i = 0; i < 4; i++) {
        int kk = ty + i * 8;
        tile[kk][tx] = W[(k0 + kk) * DD + m0 + tx];
    }
    __syncthreads();
    #pragma unroll
    for (int i = 0; i < 4; i++) {
        int mm = ty + i * 8;
        WT[(m0 + mm) * DD + k0 + tx] = f2bf(tile[tx][mm]);
    }
}

// ---------------- Wqa [1024][16] fp32 -> WqaT [16][1024] bf16 ----------------
__global__ __launch_bounds__(256) void wqa_transpose_kernel(const float* __restrict__ Wqa,
                                                            u16* __restrict__ WqaT) {
    int i = blockIdx.x * 256 + threadIdx.x;
    int h = i >> 10, k = i & 1023;
    WqaT[i] = f2bf(Wqa[k * HH + h]);
}

// ---------------- bf16 MFMA GEMM, 256x256 tile, BK=64, 8-phase schedule ----------------
// C[N,1024] = A[N,1024] @ BT^T + bias
// MODE 1: write bf16 to Cb | MODE 2: write fp32 Cf = v + bf2f(res)
// 8 waves (2M x 4N), per-wave 128x64 output, acc[8][4].
// Per K-tile: 4 phases, each {ds_read subtile || stage 1 half-tile (2 gload_lds)
//   -> barrier -> setprio(1) 16 MFMA setprio(0) -> barrier}.
// Staging plan (tile kt): p1->(kt+1).A1, p2->(kt+1).B0, p3->(kt+1).B1 into the
// OTHER buffer; p4->(kt+2).A0 into the CURRENT buffer (its A reads drained by
// phase 3's lgkmcnt + barrier). vmcnt(2) once per tile at end of p4 (leaves
// (kt+2).A0 in flight); never drains to 0 in steady state.
// XOR swizzle: 16B chunk c of row r stored at chunk-position c ^ (r & 7).
template<int MODE>
__global__ __launch_bounds__(512, 2)
void gemm256_kernel(const u16* __restrict__ A, const u16* __restrict__ BT,
                    const float* __restrict__ bias, const u16* __restrict__ res,
                    float* __restrict__ Cf, u16* __restrict__ Cb) {
    __shared__ u16 sA[2][256 * 64];
    __shared__ u16 sB[2][256 * 64];
    const int row0 = blockIdx.x * 256;
    const int col0 = blockIdx.y * 256;
    const int t = threadIdx.x;
    const int w = t >> 6, lane = t & 63;
    const int wm = w >> 2, wn = w & 3;          // 2 x 4 wave grid
    const int m16 = lane & 15, quad = lane >> 4;

    f32x4 acc[8][4];
    #pragma unroll
    for (int i = 0; i < 8; i++)
        #pragma unroll
        for (int j = 0; j < 4; j++)
            acc[i][j] = (f32x4){0.f, 0.f, 0.f, 0.f};

    // staging: thread t owns rows (half*128 + j*64 + t>>3), chunk-position t&7,
    // which must hold global chunk (t&7) ^ (row&7) = (t&7) ^ ((t>>3)&7).
    const int srow = t >> 3;                     // 0..63
    const int scol = ((t & 7) ^ (srow & 7)) * 8;
    const u16* Ag = A + (size_t)(row0 + srow) * DD + scol;
    const u16* Bg = BT + (size_t)(col0 + srow) * DD + scol;

    // stage one half-tile (2 x global_load_lds per thread) of tile `ktile`
    auto STAGE_H = [&](int ktile, int mat, int half) {
        if (ktile >= 16) return;
        const int buf = ktile & 1;
        const int k0 = ktile * 64;
        const u16* g = mat ? Bg : Ag;
        u16* s = mat ? &sB[buf][0] : &sA[buf][0];
        #pragma unroll
        for (int j = 0; j < 2; ++j)
            load_lds16(g + k0 + (size_t)(half * 128 + j * 64) * DD,
                       s + half * 8192 + j * 4096 + t * 8);
    };

    // prologue: tile0 fully, then tile1.A0; wait until tile0 landed (2 left).
    STAGE_H(0, 0, 0); STAGE_H(0, 0, 1); STAGE_H(0, 1, 0); STAGE_H(0, 1, 1);
    STAGE_H(1, 0, 0);
    asm volatile("s_waitcnt vmcnt(2)" ::: "memory");
    BAR();

    for (int kt = 0; kt < 16; ++kt) {
        const int cur = kt & 1;
        const u16* sAc = sA[cur];
        const u16* sBc = sB[cur];
        bf16x8 af[4][2], bfr[4][2];

        // ---------- phase 1: read af(lo rows) + bfr(ni 0-1); stage (kt+1).A1
        #pragma unroll
        for (int mi = 0; mi < 4; ++mi)
            #pragma unroll
            for (int ks = 0; ks < 2; ++ks)
                af[mi][ks] = *(const bf16x8*)&sAc[(wm * 128 + mi * 16 + m16) * 64 +
                                                 (((ks * 4 + quad) ^ (m16 & 7)) * 8)];
        #pragma unroll
        for (int ni = 0; ni < 2; ++ni)
            #pragma unroll
            for (int ks = 0; ks < 2; ++ks)
                bfr[ni][ks] = *(const bf16x8*)&sBc[(wn * 64 + ni * 16 + m16) * 64 +
                                                   (((ks * 4 + quad) ^ (m16 & 7)) * 8)];
        STAGE_H(kt + 1, 0, 1);
        BAR();
        __builtin_amdgcn_s_setprio(1);
        #pragma unroll
        for (int mi = 0; mi < 4; ++mi)
            #pragma unroll
            for (int ni = 0; ni < 2; ++ni)
                #pragma unroll
                for (int ks = 0; ks < 2; ++ks)
                    acc[mi][ni] = __builtin_amdgcn_mfma_f32_16x16x32_bf16(
                        af[mi][ks], bfr[ni][ks], acc[mi][ni], 0, 0, 0);
        __builtin_amdgcn_s_setprio(0);
        BAR();

        // ---------- phase 2: read bfr(ni 2-3); stage (kt+1).B0
        #pragma unroll
        for (int ni = 2; ni < 4; ++ni)
            #pragma unroll
            for (int ks = 0; ks < 2; ++ks)
                bfr[ni][ks] = *(const bf16x8*)&sBc[(wn * 64 + ni * 16 + m16) * 64 +
                                                   (((ks * 4 + quad) ^ (m16 & 7)) * 8)];
        STAGE_H(kt + 1, 1, 0);
        BAR();
        __builtin_amdgcn_s_setprio(1);
        #pragma unroll
        for (int mi = 0; mi < 4; ++mi)
            #pragma unroll
            for (int ni = 2; ni < 4; ++ni)
                #pragma unroll
                for (int ks = 0; ks < 2; ++ks)
                    acc[mi][ni] = __builtin_amdgcn_mfma_f32_16x16x32_bf16(
                        af[mi][ks], bfr[ni][ks], acc[mi][ni], 0, 0, 0);
        __builtin_amdgcn_s_setprio(0);
        BAR();

        // ---------- phase 3: read af(hi rows, reuse regs); stage (kt+1).B1
        #pragma unroll
        for (int mi = 0; mi < 4; ++mi)
            #pragma unroll
            for (int ks = 0; ks < 2; ++ks)
                af[mi][ks] = *(const bf16x8*)&sAc[(wm * 128 + (4 + mi) * 16 + m16) * 64 +
                                                 (((ks * 4 + quad) ^ (m16 & 7)) * 8)];
        STAGE_H(kt + 1, 1, 1);
        BAR();
        __builtin_amdgcn_s_setprio(1);
        #pragma unroll
        for (int mi = 0; mi < 4; ++mi)
            #pragma unroll
            for (int ni = 0; ni < 2; ++ni)
                #pragma unroll
                for (int ks = 0; ks < 2; ++ks)
                    acc[4 + mi][ni] = __builtin_amdgcn_mfma_f32_16x16x32_bf16(
                        af[mi][ks], bfr[ni][ks], acc[4 + mi][ni], 0, 0, 0);
        __builtin_amdgcn_s_setprio(0);
        BAR();

        // ---------- phase 4: no reads; stage (kt+2).A0 into current buffer
        // (safe: all A reads of this buffer completed before phase 3's barrier)
        STAGE_H(kt + 2, 0, 0);
        BAR();
        __builtin_amdgcn_s_setprio(1);
        #pragma unroll
        for (int mi = 0; mi < 4; ++mi)
            #pragma unroll
            for (int ni = 2; ni < 4; ++ni)
                #pragma unroll
                for (int ks = 0; ks < 2; ++ks)
                    acc[4 + mi][ni] = __builtin_amdgcn_mfma_f32_16x16x32_bf16(
                        af[mi][ks], bfr[ni][ks], acc[4 + mi][ni], 0, 0, 0);
        __builtin_amdgcn_s_setprio(0);
        // counted wait once per tile: drains through (kt+1).B1, leaves (kt+2).A0
        if (kt < 14) asm volatile("s_waitcnt vmcnt(2)" ::: "memory");
        else         asm volatile("s_waitcnt vmcnt(0)" ::: "memory");
        BAR();
    }

    #pragma unroll
    for (int mi = 0; mi < 8; ++mi) {
        #pragma unroll
        for (int r = 0; r < 4; ++r) {
            int row = row0 + wm * 128 + mi * 16 + quad * 4 + r;
            #pragma unroll
            for (int ni = 0; ni < 4; ++ni) {
                int col = col0 + wn * 64 + ni * 16 + m16;
                float v = acc[mi][ni][r] + bias[col];
                size_t idx = (size_t)row * DD + col;
                if (MODE == 1) Cb[idx] = f2bf(v);
                else Cf[idx] = v + bf2f(res[idx]);
            }
        }
    }
}

// ---------------- raw qscore via MFMA, K-split 4 -> separate slices ----------------
// grid = (NROWS/64, 4). qraw[split][b][h][s] = sum_{k in split} q[s][k]*Wqa[k][h]
__global__ __launch_bounds__(256)
void qscore_mfma_kernel(const u16* __restrict__ qbf, const u16* __restrict__ WqaT,
                        float* __restrict__ qraw) {
    int w = threadIdx.x >> 6, lane = threadIdx.x & 63;
    int row0 = blockIdx.x * 64 + w * 16;
    int kbase = blockIdx.y * 256;
    int m16 = lane & 15, quad = lane >> 4;
    f32x4 acc = (f32x4){0.f, 0.f, 0.f, 0.f};
    const u16* ap = qbf + (size_t)(row0 + m16) * DD + kbase + quad * 8;
    const u16* bp = WqaT + (size_t)m16 * DD + kbase + quad * 8;
    #pragma unroll
    for (int kk = 0; kk < 256; kk += 32) {
        bf16x8 a = *(const bf16x8*)(ap + kk);
        bf16x8 b = *(const bf16x8*)(bp + kk);
        acc = __builtin_amdgcn_mfma_f32_16x16x32_bf16(a, b, acc, 0, 0, 0);
    }
    #pragma unroll
    for (int r = 0; r < 4; r++) {
        int grow = row0 + quad * 4 + r;
        int b = grow >> 11, sidx = grow & 2047;
        qraw[((size_t)(blockIdx.y * BB + b) * HH + m16) * SS + sidx] = acc[r];
    }
}

// ---------------- softmax over S, writes slice 0 ----------------
// EPI: x = sum of 4 K-split slices, then (x+bqa[h])*scale+mask
template<bool EPI>
__global__ __launch_bounds__(256)
void softmax_kernel(float* __restrict__ score, const float* __restrict__ bqa,
                    const float* __restrict__ mask) {
    int bh = blockIdx.x;
    int b = bh >> 4, h = bh & 15;
    float* srow = score + ((size_t)bh << 11);
    __shared__ float rm[4], rs[4];
    int t = threadIdx.x;

    float v[8];
    float m = -1e30f;
    #pragma unroll
    for (int i = 0; i < 8; i++) {
        int off = t + i * 256;
        float x;
        if (EPI) {
            x = srow[off] + srow[off + QSLICE] + srow[off + 2 * QSLICE] + srow[off + 3 * QSLICE];
            x = (x + bqa[h]) * 0.125f + mask[b * SS + off];
        } else {
            x = srow[off];
        }
        v[i] = x; m = fmaxf(m, x);
    }
    #pragma unroll
    for (int off = 32; off; off >>= 1) m = fmaxf(m, __shfl_xor(m, off));
    if ((t & 63) == 0) rm[t >> 6] = m;
    __syncthreads();
    m = fmaxf(fmaxf(rm[0], rm[1]), fmaxf(rm[2], rm[3]));

    float sum = 0.f;
    #pragma unroll
    for (int i = 0; i < 8; i++) { v[i] = __expf(v[i] - m); sum += v[i]; }
    #pragma unroll
    for (int off = 32; off; off >>= 1) sum += __shfl_xor(sum, off);
    if ((t & 63) == 0) rs[t >> 6] = sum;
    __syncthreads();
    float inv = 1.0f / (rs[0] + rs[1] + rs[2] + rs[3]);
    #pragma unroll
    for (int i = 0; i < 8; i++) srow[t + i * 256] = v[i] * inv;
}

// ---------------- pooled[b,:,:] += sum_{s in 32-chunk} w[b,h,s] * X[b,s,:] ----------------
// grid = (BB, SS/32). Full 2KB rows read coalesced; lane owns (h=lane>>2, 16 dims).
__global__ __launch_bounds__(256)
void pool_kernel(const float* __restrict__ w, const u16* __restrict__ X,
                 float* __restrict__ pooled) {
    int b = blockIdx.x;
    int s0 = blockIdx.y * 32;
    int t = threadIdx.x;
    int wid = t >> 6, lane = t & 63;
    int h = lane >> 2;
    __shared__ float sw[16 * 33];
    __shared__ float pr[4][64 * 17];
    {
        int hh = t >> 4, si = t & 15;
        const float* wr = w + ((size_t)(b * HH + hh) << 11) + s0;
        sw[hh * 33 + si] = wr[si];
        sw[hh * 33 + si + 16] = wr[si + 16];
    }
    __syncthreads();
    float acc[16];
    #pragma unroll
    for (int j = 0; j < 16; j++) acc[j] = 0.f;
    const u16* xbase = X + ((size_t)(b * SS + s0 + wid * 8) << 10) + lane * 16;
    #pragma unroll
    for (int rr = 0; rr < 8; rr++) {
        float ws = sw[h * 33 + wid * 8 + rr];
        const uint4* xp = (const uint4*)(xbase + (size_t)rr * DD);
        uint4 x0 = xp[0], x1 = xp[1];
        unsigned xw[8] = {x0.x, x0.y, x0.z, x0.w, x1.x, x1.y, x1.z, x1.w};
        #pragma unroll
        for (int i2 = 0; i2 < 8; i2++) {
            union { unsigned u; float f; } lo, hi;
            lo.u = xw[i2] << 16; hi.u = xw[i2] & 0xffff0000u;
            acc[2 * i2]     += ws * lo.f;
            acc[2 * i2 + 1] += ws * hi.f;
        }
    }
    #pragma unroll
    for (int j = 0; j < 16; j++) pr[wid][lane * 17 + j] = acc[j];
    __syncthreads();
    #pragma unroll
    for (int i = 0; i < 4; i++) {
        int idx = t + i * 256;                       // 0..1023 = lane'*16 + j
        int l2 = idx >> 4, j2 = idx & 15;
        float v = pr[0][l2 * 17 + j2] + pr[1][l2 * 17 + j2] +
                  pr[2][l2 * 17 + j2] + pr[3][l2 * 17 + j2];
        int od = (l2 >> 2) * 64 + (l2 & 3) * 16 + j2;  // h*64 + d
        atomicAdd(&pooled[b * DD + od], v);
    }
}

// ---------------- qk_score[b,h,s] = (k[b,s,h*64:]·pq[b,h,:])*scale + mask ----------------
__global__ __launch_bounds__(256)
void qkscore_kernel(const u16* __restrict__ kbf, const float* __restrict__ pq,
                    const float* __restrict__ mask, float* __restrict__ qkscore) {
    int row = blockIdx.x * 4 + (threadIdx.x >> 6);
    int lane = threadIdx.x & 63;
    int b = row >> 11, s = row & 2047;
    int h = lane >> 2, dp = lane & 3;
    const u16* kp = kbf + (size_t)row * DD + h * 64 + dp * 16;
    const float* pqp = pq + (size_t)(b * HH + h) * 64 + dp * 16;
    const uint4* kp4 = (const uint4*)kp;
    uint4 ka = kp4[0], kb4 = kp4[1];
    unsigned kw[8] = {ka.x, ka.y, ka.z, ka.w, kb4.x, kb4.y, kb4.z, kb4.w};
    float acc = 0.f;
    #pragma unroll
    for (int i = 0; i < 8; i++) {
        union { unsigned u; float f; } lo, hi;
        lo.u = kw[i] << 16;
        hi.u = kw[i] & 0xffff0000u;
        acc += lo.f * pqp[2 * i] + hi.f * pqp[2 * i + 1];
    }
    acc += __shfl_xor(acc, 1);
    acc += __shfl_xor(acc, 2);
    if (dp == 0) qkscore[(size_t)(b * HH + h) * SS + s] = acc * 0.125f + mask[b * SS + s];
}

// ---------------- weighted_bf[b,s,h*64+d] = bf16(pk[b,h,d]*q_bf[b,s,h*64+d]) ----------------
__global__ __launch_bounds__(256)
void weighted_kernel(const u16* __restrict__ qbf, const float* __restrict__ pk,
                     u16* __restrict__ wout) {
    int i = blockIdx.x * 256 + threadIdx.x;
    int row = i >> 8;
    int c0 = (i & 255) << 2;
    int b = row >> 11;
    int h = c0 >> 6, d = c0 & 63;
    ushort4 qv = ((const ushort4*)qbf)[i];
    const float4 pv = *(const float4*)(pk + (size_t)(b * HH + h) * 64 + d);
    ushort4 o;
    o.x = f2bf(bf2f(qv.x) * pv.x); o.y = f2bf(bf2f(qv.y) * pv.y);
    o.z = f2bf(bf2f(qv.z) * pv.z); o.w = f2bf(bf2f(qv.w) * pv.w);
    ((ushort4*)wout)[i] = o;
}

extern "C" void kernel_launch(void* const* d_in, const int* in_sizes, int n_in,
                              void* d_out, int out_size, void* d_ws, size_t ws_size,
                              hipStream_t stream) {
    const float* hs   = (const float*)d_in[0];
    const float* mask = (const float*)d_in[1];
    const float* Wq   = (const float*)d_in[2];
    const float* bq   = (const float*)d_in[3];
    const float* Wqa  = (const float*)d_in[4];
    const float* bqa  = (const float*)d_in[5];
    const float* Wk   = (const float*)d_in[6];
    const float* bk   = (const float*)d_in[7];
    const float* Wt   = (const float*)d_in[8];
    const float* bt   = (const float*)d_in[9];
    float* out = (float*)d_out;

    char* ws = (char*)d_ws;
    u16*   hs_bf = (u16*)ws;   ws += (size_t)NROWS * DD * 2;
    u16*   WqT   = (u16*)ws;   ws += (size_t)DD * DD * 2;
    u16*   WkT   = (u16*)ws;   ws += (size_t)DD * DD * 2;
    u16*   WtT   = (u16*)ws;   ws += (size_t)DD * DD * 2;
    u16*   WqaT  = (u16*)ws;   ws += (size_t)HH * DD * 2;
    u16*   q_bf  = (u16*)ws;   ws += (size_t)NROWS * DD * 2;
    u16*   k_bf  = (u16*)ws;   ws += (size_t)NROWS * DD * 2;
    float* qraw  = (float*)ws; ws += QSLICE * 4 * 4;   // 4 K-split slices
    float* qksc  = (float*)ws; ws += (size_t)BB * HH * SS * 4;
    float* pq    = (float*)ws; ws += (size_t)BB * HH * 64 * 4;
    float* pk    = (float*)ws; ws += (size_t)BB * HH * 64 * 4;
    u16*   wbf   = hs_bf;  // alias: hs_bf dead after gemm k, wbf written after

    int n4 = NROWS * DD / 4;
    cast_bf16_kernel<<<n4 / 256, 256, 0, stream>>>(hs, hs_bf, n4);
    transpose_cast_kernel<<<dim3(32, 32), 256, 0, stream>>>(Wq, WqT);
    transpose_cast_kernel<<<dim3(32, 32), 256, 0, stream>>>(Wk, WkT);
    transpose_cast_kernel<<<dim3(32, 32), 256, 0, stream>>>(Wt, WtT);
    wqa_transpose_kernel<<<HH * DD / 256, 256, 0, stream>>>(Wqa, WqaT);

    hipMemsetAsync(pq, 0, (size_t)BB * HH * 64 * 4, stream);
    hipMemsetAsync(pk, 0, (size_t)BB * HH * 64 * 4, stream);

    gemm256_kernel<1><<<dim3(NROWS / 256, DD / 256), 512, 0, stream>>>(hs_bf, WqT, bq, nullptr, nullptr, q_bf);
    gemm256_kernel<1><<<dim3(NROWS / 256, DD / 256), 512, 0, stream>>>(hs_bf, WkT, bk, nullptr, nullptr, k_bf);

    qscore_mfma_kernel<<<dim3(NROWS / 64, 4), 256, 0, stream>>>(q_bf, WqaT, qraw);
    softmax_kernel<true><<<BB * HH, 256, 0, stream>>>(qraw, bqa, mask);
    pool_kernel<<<dim3(BB, SS / 32), 256, 0, stream>>>(qraw, q_bf, pq);
    qkscore_kernel<<<NROWS / 4, 256, 0, stream>>>(k_bf, pq, mask, qksc);
    softmax_kernel<false><<<BB * HH, 256, 0, stream>>>(qksc, nullptr, nullptr);
    pool_kernel<<<dim3(BB, SS / 32), 256, 0, stream>>>(qksc, k_bf, pk);
    weighted_kernel<<<n4 / 256, 256, 0, stream>>>(q_bf, pk, wbf);

    gemm256_kernel<2><<<dim3(NROWS / 256, DD / 256), 512, 0, stream>>>(wbf, WtT, bt, q_bf, out, nullptr);
}

// Round 3
// 309.592 us; speedup vs baseline: 1.0774x; 1.0110x over previous
//
#include <hip/hip_runtime.h>
#include <hip/hip_bf16.h>
#include <math.h>

#define BB 8
#define SS 2048
#define DD 1024
#define HH 16
#define DHH 64
#define NROWS (BB*SS)   // 16384
#define QSLICE ((size_t)BB * HH * SS)   // elems per qscore K-split slice

typedef unsigned short u16;
typedef __attribute__((ext_vector_type(8))) __bf16 bf16x8;
typedef __attribute__((ext_vector_type(4))) float f32x4;

__device__ __forceinline__ u16 f2bf(float f) {
    union { float f; unsigned u; } v; v.f = f;
    unsigned r = v.u + 0x7fffu + ((v.u >> 16) & 1u);
    return (u16)(r >> 16);
}
__device__ __forceinline__ float bf2f(u16 b) {
    union { unsigned u; float f; } v; v.u = ((unsigned)b) << 16;
    return v.f;
}

__device__ __forceinline__ void load_lds16(const void* g, void* l) {
    __builtin_amdgcn_global_load_lds(
        (const __attribute__((address_space(1))) unsigned int*)g,
        (__attribute__((address_space(3))) unsigned int*)l,
        16, 0, 0);
}

// raw workgroup barrier WITHOUT the vmcnt(0)/lgkmcnt(0) drain __syncthreads forces.
#define BAR() do { asm volatile("" ::: "memory"); \
                   __builtin_amdgcn_s_barrier();  \
                   asm volatile("" ::: "memory"); } while (0)

// ---------------- cast hs fp32 -> bf16 ----------------
__global__ __launch_bounds__(256) void cast_bf16_kernel(const float* __restrict__ in,
                                                        u16* __restrict__ out, int n4) {
    int i = blockIdx.x * 256 + threadIdx.x;
    if (i >= n4) return;
    float4 v = ((const float4*)in)[i];
    ushort4 o;
    o.x = f2bf(v.x); o.y = f2bf(v.y); o.z = f2bf(v.z); o.w = f2bf(v.w);
    ((ushort4*)out)[i] = o;
}

// ---------------- W [K,M] fp32 -> WT [M,K] bf16 ----------------
__global__ __launch_bounds__(256) void transpose_cast_kernel(const float* __restrict__ W,
                                                             u16* __restrict__ WT) {
    __shared__ float tile[32][33];
    int m0 = blockIdx.x * 32, k0 = blockIdx.y * 32;
    int tx = threadIdx.x & 31, ty = threadIdx.x >> 5;
    #pragma unroll
    for (int i = 0; i < 4; i++) {
        int kk = ty + i * 8;
        tile[kk][tx] = W[(k0 + kk) * DD + m0 + tx];
    }
    __syncthreads();
    #pragma unroll
    for (int i = 0; i < 4; i++) {
        int mm = ty + i * 8;
        WT[(m0 + mm) * DD + k0 + tx] = f2bf(tile[tx][mm]);
    }
}

// ---------------- Wqa [1024][16] fp32 -> WqaT [16][1024] bf16 ----------------
__global__ __launch_bounds__(256) void wqa_transpose_kernel(const float* __restrict__ Wqa,
                                                            u16* __restrict__ WqaT) {
    int i = blockIdx.x * 256 + threadIdx.x;
    int h = i >> 10, k = i & 1023;
    WqaT[i] = f2bf(Wqa[k * HH + h]);
}

// ---------------- bf16 MFMA GEMM, 256x256 tile, BK=64, 8-phase schedule ----------------
// C = A[16384,1024] @ BT^T + bias
// MODE 1: merged Q|K GEMM. grid (64, 8): by<4 -> (b0=bq, C0=q_bf); by>=4 -> (b1=bk, C1=k_bf).
//         BT has 2048 rows (WqT||WkT adjacent). bf16 C-tile staged via LDS -> dwordx4
//         stores (kills the 2x write amplification of 2B scattered stores).
// MODE 2: grid (64, 4). Cf = v + bias + bf2f(res); float4 stores (full 64B lines),
//         res read as coalesced ushort4.
// OPERAND-SWAPPED MFMA: mfma(bfr, af) so lane (m16,quad) reg r holds
//   C[row = wm*128+mi*16+m16][col = wn*64+ni*16+quad*4 + r]  -> 4 consecutive cols/reg.
// Loop schedule unchanged from round 2 (4 phases/K-tile, counted vmcnt(2)).
template<int MODE>
__global__ __launch_bounds__(512, 2)
void gemm256_kernel(const u16* __restrict__ A, const u16* __restrict__ BT,
                    const float* __restrict__ b0, const float* __restrict__ b1,
                    const u16* __restrict__ res, float* __restrict__ Cf,
                    u16* __restrict__ C0, u16* __restrict__ C1) {
    // carve: sA[buf] = smem + buf*16384, sB[buf] = smem + 32768 + buf*16384 (128KB)
    // epilogue (MODE 1): sC[256][272] u16 = 139264 B aliases the whole pool.
    __shared__ u16 smem[69632];
    const int by = blockIdx.y;
    const int row0 = blockIdx.x * 256;
    const int bcol0 = by * 256;                      // column in BT row space
    const int colg0 = (MODE == 1) ? (bcol0 & 1023) : bcol0;  // column in output buffer
    const float* bias = (MODE == 1 && by >= 4) ? b1 : b0;
    u16* Cb = (MODE == 1 && by >= 4) ? C1 : C0;

    const int t = threadIdx.x;
    const int w = t >> 6, lane = t & 63;
    const int wm = w >> 2, wn = w & 3;          // 2 x 4 wave grid
    const int m16 = lane & 15, quad = lane >> 4;

    f32x4 acc[8][4];
    #pragma unroll
    for (int i = 0; i < 8; i++)
        #pragma unroll
        for (int j = 0; j < 4; j++)
            acc[i][j] = (f32x4){0.f, 0.f, 0.f, 0.f};

    // staging: thread t owns rows (half*128 + j*64 + t>>3), chunk-position t&7,
    // which must hold global chunk (t&7) ^ (row&7) = (t&7) ^ ((t>>3)&7).
    const int srow = t >> 3;                     // 0..63
    const int scol = ((t & 7) ^ (srow & 7)) * 8;
    const u16* Ag = A + (size_t)(row0 + srow) * DD + scol;
    const u16* Bg = BT + (size_t)(bcol0 + srow) * DD + scol;

    // stage one half-tile (2 x global_load_lds per thread) of tile `ktile`
    auto STAGE_H = [&](int ktile, int mat, int half) {
        if (ktile >= 16) return;
        const int buf = ktile & 1;
        const int k0 = ktile * 64;
        const u16* g = mat ? Bg : Ag;
        u16* s = smem + mat * 32768 + buf * 16384;
        #pragma unroll
        for (int j = 0; j < 2; ++j)
            load_lds16(g + k0 + (size_t)(half * 128 + j * 64) * DD,
                       s + half * 8192 + j * 4096 + t * 8);
    };

    // prologue: tile0 fully, then tile1.A0; wait until tile0 landed (2 left).
    STAGE_H(0, 0, 0); STAGE_H(0, 0, 1); STAGE_H(0, 1, 0); STAGE_H(0, 1, 1);
    STAGE_H(1, 0, 0);
    asm volatile("s_waitcnt vmcnt(2)" ::: "memory");
    BAR();

    for (int kt = 0; kt < 16; ++kt) {
        const int cur = kt & 1;
        const u16* sAc = smem + cur * 16384;
        const u16* sBc = smem + 32768 + cur * 16384;
        bf16x8 af[4][2], bfr[4][2];

        // ---------- phase 1: read af(lo rows) + bfr(ni 0-1); stage (kt+1).A1
        #pragma unroll
        for (int mi = 0; mi < 4; ++mi)
            #pragma unroll
            for (int ks = 0; ks < 2; ++ks)
                af[mi][ks] = *(const bf16x8*)&sAc[(wm * 128 + mi * 16 + m16) * 64 +
                                                 (((ks * 4 + quad) ^ (m16 & 7)) * 8)];
        #pragma unroll
        for (int ni = 0; ni < 2; ++ni)
            #pragma unroll
            for (int ks = 0; ks < 2; ++ks)
                bfr[ni][ks] = *(const bf16x8*)&sBc[(wn * 64 + ni * 16 + m16) * 64 +
                                                   (((ks * 4 + quad) ^ (m16 & 7)) * 8)];
        STAGE_H(kt + 1, 0, 1);
        BAR();
        __builtin_amdgcn_s_setprio(1);
        #pragma unroll
        for (int mi = 0; mi < 4; ++mi)
            #pragma unroll
            for (int ni = 0; ni < 2; ++ni)
                #pragma unroll
                for (int ks = 0; ks < 2; ++ks)
                    acc[mi][ni] = __builtin_amdgcn_mfma_f32_16x16x32_bf16(
                        bfr[ni][ks], af[mi][ks], acc[mi][ni], 0, 0, 0);
        __builtin_amdgcn_s_setprio(0);
        BAR();

        // ---------- phase 2: read bfr(ni 2-3); stage (kt+1).B0
        #pragma unroll
        for (int ni = 2; ni < 4; ++ni)
            #pragma unroll
            for (int ks = 0; ks < 2; ++ks)
                bfr[ni][ks] = *(const bf16x8*)&sBc[(wn * 64 + ni * 16 + m16) * 64 +
                                                   (((ks * 4 + quad) ^ (m16 & 7)) * 8)];
        STAGE_H(kt + 1, 1, 0);
        BAR();
        __builtin_amdgcn_s_setprio(1);
        #pragma unroll
        for (int mi = 0; mi < 4; ++mi)
            #pragma unroll
            for (int ni = 2; ni < 4; ++ni)
                #pragma unroll
                for (int ks = 0; ks < 2; ++ks)
                    acc[mi][ni] = __builtin_amdgcn_mfma_f32_16x16x32_bf16(
                        bfr[ni][ks], af[mi][ks], acc[mi][ni], 0, 0, 0);
        __builtin_amdgcn_s_setprio(0);
        BAR();

        // ---------- phase 3: read af(hi rows, reuse regs); stage (kt+1).B1
        #pragma unroll
        for (int mi = 0; mi < 4; ++mi)
            #pragma unroll
            for (int ks = 0; ks < 2; ++ks)
                af[mi][ks] = *(const bf16x8*)&sAc[(wm * 128 + (4 + mi) * 16 + m16) * 64 +
                                                 (((ks * 4 + quad) ^ (m16 & 7)) * 8)];
        STAGE_H(kt + 1, 1, 1);
        BAR();
        __builtin_amdgcn_s_setprio(1);
        #pragma unroll
        for (int mi = 0; mi < 4; ++mi)
            #pragma unroll
            for (int ni = 0; ni < 2; ++ni)
                #pragma unroll
                for (int ks = 0; ks < 2; ++ks)
                    acc[4 + mi][ni] = __builtin_amdgcn_mfma_f32_16x16x32_bf16(
                        bfr[ni][ks], af[mi][ks], acc[4 + mi][ni], 0, 0, 0);
        __builtin_amdgcn_s_setprio(0);
        BAR();

        // ---------- phase 4: no reads; stage (kt+2).A0 into current buffer
        STAGE_H(kt + 2, 0, 0);
        BAR();
        __builtin_amdgcn_s_setprio(1);
        #pragma unroll
        for (int mi = 0; mi < 4; ++mi)
            #pragma unroll
            for (int ni = 2; ni < 4; ++ni)
                #pragma unroll
                for (int ks = 0; ks < 2; ++ks)
                    acc[4 + mi][ni] = __builtin_amdgcn_mfma_f32_16x16x32_bf16(
                        bfr[ni][ks], af[mi][ks], acc[4 + mi][ni], 0, 0, 0);
        __builtin_amdgcn_s_setprio(0);
        if (kt < 14) asm volatile("s_waitcnt vmcnt(2)" ::: "memory");
        else         asm volatile("s_waitcnt vmcnt(0)" ::: "memory");
        BAR();
    }

    // ---------------- epilogue ----------------
    // lane (m16,quad) reg r = C[wm*128+mi*16+m16][wn*64+ni*16+quad*4+r]
    u16* sC = smem;                               // [256][272] u16, MODE 1 only
    #pragma unroll
    for (int mi = 0; mi < 8; ++mi) {
        const int lrow = wm * 128 + mi * 16 + m16;           // 0..255 in tile
        #pragma unroll
        for (int ni = 0; ni < 4; ++ni) {
            const int lcol = wn * 64 + ni * 16 + quad * 4;   // 0..255 in tile
            const float4 bv = *(const float4*)&bias[colg0 + lcol];
            if (MODE == 1) {
                ushort4 o;
                o.x = f2bf(acc[mi][ni][0] + bv.x);
                o.y = f2bf(acc[mi][ni][1] + bv.y);
                o.z = f2bf(acc[mi][ni][2] + bv.z);
                o.w = f2bf(acc[mi][ni][3] + bv.w);
                *(ushort4*)&sC[(size_t)lrow * 272 + lcol] = o;
            } else {
                const size_t idx = (size_t)(row0 + lrow) * DD + colg0 + lcol;
                const ushort4 rv = *(const ushort4*)&res[idx];
                float4 o;
                o.x = acc[mi][ni][0] + bv.x + bf2f(rv.x);
                o.y = acc[mi][ni][1] + bv.y + bf2f(rv.y);
                o.z = acc[mi][ni][2] + bv.z + bf2f(rv.z);
                o.w = acc[mi][ni][3] + bv.w + bf2f(rv.w);
                *(float4*)&Cf[idx] = o;
            }
        }
    }
    if (MODE == 1) {
        __syncthreads();
        #pragma unroll
        for (int it = 0; it < 16; ++it) {
            const int r = it * 16 + (t >> 5);
            const int c = t & 31;
            uint4 v = *(const uint4*)&sC[(size_t)r * 272 + c * 8];
            *(uint4*)&Cb[(size_t)(row0 + r) * DD + colg0 + c * 8] = v;
        }
    }
}

// ---------------- raw qscore via MFMA, K-split 4 -> separate slices ----------------
// grid = (NROWS/64, 4). qraw[split][b][h][s] = sum_{k in split} q[s][k]*Wqa[k][h]
__global__ __launch_bounds__(256)
void qscore_mfma_kernel(const u16* __restrict__ qbf, const u16* __restrict__ WqaT,
                        float* __restrict__ qraw) {
    int w = threadIdx.x >> 6, lane = threadIdx.x & 63;
    int row0 = blockIdx.x * 64 + w * 16;
    int kbase = blockIdx.y * 256;
    int m16 = lane & 15, quad = lane >> 4;
    f32x4 acc = (f32x4){0.f, 0.f, 0.f, 0.f};
    const u16* ap = qbf + (size_t)(row0 + m16) * DD + kbase + quad * 8;
    const u16* bp = WqaT + (size_t)m16 * DD + kbase + quad * 8;
    #pragma unroll
    for (int kk = 0; kk < 256; kk += 32) {
        bf16x8 a = *(const bf16x8*)(ap + kk);
        bf16x8 b = *(const bf16x8*)(bp + kk);
        acc = __builtin_amdgcn_mfma_f32_16x16x32_bf16(a, b, acc, 0, 0, 0);
    }
    #pragma unroll
    for (int r = 0; r < 4; r++) {
        int grow = row0 + quad * 4 + r;
        int b = grow >> 11, sidx = grow & 2047;
        qraw[((size_t)(blockIdx.y * BB + b) * HH + m16) * SS + sidx] = acc[r];
    }
}

// ---------------- softmax over S, writes slice 0 ----------------
// EPI: x = sum of 4 K-split slices, then (x+bqa[h])*scale+mask
template<bool EPI>
__global__ __launch_bounds__(256)
void softmax_kernel(float* __restrict__ score, const float* __restrict__ bqa,
                    const float* __restrict__ mask) {
    int bh = blockIdx.x;
    int b = bh >> 4, h = bh & 15;
    float* srow = score + ((size_t)bh << 11);
    __shared__ float rm[4], rs[4];
    int t = threadIdx.x;

    float v[8];
    float m = -1e30f;
    #pragma unroll
    for (int i = 0; i < 8; i++) {
        int off = t + i * 256;
        float x;
        if (EPI) {
            x = srow[off] + srow[off + QSLICE] + srow[off + 2 * QSLICE] + srow[off + 3 * QSLICE];
            x = (x + bqa[h]) * 0.125f + mask[b * SS + off];
        } else {
            x = srow[off];
        }
        v[i] = x; m = fmaxf(m, x);
    }
    #pragma unroll
    for (int off = 32; off; off >>= 1) m = fmaxf(m, __shfl_xor(m, off));
    if ((t & 63) == 0) rm[t >> 6] = m;
    __syncthreads();
    m = fmaxf(fmaxf(rm[0], rm[1]), fmaxf(rm[2], rm[3]));

    float sum = 0.f;
    #pragma unroll
    for (int i = 0; i < 8; i++) { v[i] = __expf(v[i] - m); sum += v[i]; }
    #pragma unroll
    for (int off = 32; off; off >>= 1) sum += __shfl_xor(sum, off);
    if ((t & 63) == 0) rs[t >> 6] = sum;
    __syncthreads();
    float inv = 1.0f / (rs[0] + rs[1] + rs[2] + rs[3]);
    #pragma unroll
    for (int i = 0; i < 8; i++) srow[t + i * 256] = v[i] * inv;
}

// ---------------- pooled[b,:,:] += sum_{s in 32-chunk} w[b,h,s] * X[b,s,:] ----------------
// grid = (BB, SS/32). Full 2KB rows read coalesced; lane owns (h=lane>>2, 16 dims).
__global__ __launch_bounds__(256)
void pool_kernel(const float* __restrict__ w, const u16* __restrict__ X,
                 float* __restrict__ pooled) {
    int b = blockIdx.x;
    int s0 = blockIdx.y * 32;
    int t = threadIdx.x;
    int wid = t >> 6, lane = t & 63;
    int h = lane >> 2;
    __shared__ float sw[16 * 33];
    __shared__ float pr[4][64 * 17];
    {
        int hh = t >> 4, si = t & 15;
        const float* wr = w + ((size_t)(b * HH + hh) << 11) + s0;
        sw[hh * 33 + si] = wr[si];
        sw[hh * 33 + si + 16] = wr[si + 16];
    }
    __syncthreads();
    float acc[16];
    #pragma unroll
    for (int j = 0; j < 16; j++) acc[j] = 0.f;
    const u16* xbase = X + ((size_t)(b * SS + s0 + wid * 8) << 10) + lane * 16;
    #pragma unroll
    for (int rr = 0; rr < 8; rr++) {
        float ws = sw[h * 33 + wid * 8 + rr];
        const uint4* xp = (const uint4*)(xbase + (size_t)rr * DD);
        uint4 x0 = xp[0], x1 = xp[1];
        unsigned xw[8] = {x0.x, x0.y, x0.z, x0.w, x1.x, x1.y, x1.z, x1.w};
        #pragma unroll
        for (int i2 = 0; i2 < 8; i2++) {
            union { unsigned u; float f; } lo, hi;
            lo.u = xw[i2] << 16; hi.u = xw[i2] & 0xffff0000u;
            acc[2 * i2]     += ws * lo.f;
            acc[2 * i2 + 1] += ws * hi.f;
        }
    }
    #pragma unroll
    for (int j = 0; j < 16; j++) pr[wid][lane * 17 + j] = acc[j];
    __syncthreads();
    #pragma unroll
    for (int i = 0; i < 4; i++) {
        int idx = t + i * 256;                       // 0..1023 = lane'*16 + j
        int l2 = idx >> 4, j2 = idx & 15;
        float v = pr[0][l2 * 17 + j2] + pr[1][l2 * 17 + j2] +
                  pr[2][l2 * 17 + j2] + pr[3][l2 * 17 + j2];
        int od = (l2 >> 2) * 64 + (l2 & 3) * 16 + j2;  // h*64 + d
        atomicAdd(&pooled[b * DD + od], v);
    }
}

// ---------------- qk_score[b,h,s] = (k[b,s,h*64:]·pq[b,h,:])*scale + mask ----------------
__global__ __launch_bounds__(256)
void qkscore_kernel(const u16* __restrict__ kbf, const float* __restrict__ pq,
                    const float* __restrict__ mask, float* __restrict__ qkscore) {
    int row = blockIdx.x * 4 + (threadIdx.x >> 6);
    int lane = threadIdx.x & 63;
    int b = row >> 11, s = row & 2047;
    int h = lane >> 2, dp = lane & 3;
    const u16* kp = kbf + (size_t)row * DD + h * 64 + dp * 16;
    const float* pqp = pq + (size_t)(b * HH + h) * 64 + dp * 16;
    const uint4* kp4 = (const uint4*)kp;
    uint4 ka = kp4[0], kb4 = kp4[1];
    unsigned kw[8] = {ka.x, ka.y, ka.z, ka.w, kb4.x, kb4.y, kb4.z, kb4.w};
    float acc = 0.f;
    #pragma unroll
    for (int i = 0; i < 8; i++) {
        union { unsigned u; float f; } lo, hi;
        lo.u = kw[i] << 16;
        hi.u = kw[i] & 0xffff0000u;
        acc += lo.f * pqp[2 * i] + hi.f * pqp[2 * i + 1];
    }
    acc += __shfl_xor(acc, 1);
    acc += __shfl_xor(acc, 2);
    if (dp == 0) qkscore[(size_t)(b * HH + h) * SS + s] = acc * 0.125f + mask[b * SS + s];
}

// ---------------- weighted_bf[b,s,h*64+d] = bf16(pk[b,h,d]*q_bf[b,s,h*64+d]) ----------------
__global__ __launch_bounds__(256)
void weighted_kernel(const u16* __restrict__ qbf, const float* __restrict__ pk,
                     u16* __restrict__ wout) {
    int i = blockIdx.x * 256 + threadIdx.x;
    int row = i >> 8;
    int c0 = (i & 255) << 2;
    int b = row >> 11;
    int h = c0 >> 6, d = c0 & 63;
    ushort4 qv = ((const ushort4*)qbf)[i];
    const float4 pv = *(const float4*)(pk + (size_t)(b * HH + h) * 64 + d);
    ushort4 o;
    o.x = f2bf(bf2f(qv.x) * pv.x); o.y = f2bf(bf2f(qv.y) * pv.y);
    o.z = f2bf(bf2f(qv.z) * pv.z); o.w = f2bf(bf2f(qv.w) * pv.w);
    ((ushort4*)wout)[i] = o;
}

extern "C" void kernel_launch(void* const* d_in, const int* in_sizes, int n_in,
                              void* d_out, int out_size, void* d_ws, size_t ws_size,
                              hipStream_t stream) {
    const float* hs   = (const float*)d_in[0];
    const float* mask = (const float*)d_in[1];
    const float* Wq   = (const float*)d_in[2];
    const float* bq   = (const float*)d_in[3];
    const float* Wqa  = (const float*)d_in[4];
    const float* bqa  = (const float*)d_in[5];
    const float* Wk   = (const float*)d_in[6];
    const float* bk   = (const float*)d_in[7];
    const float* Wt   = (const float*)d_in[8];
    const float* bt   = (const float*)d_in[9];
    float* out = (float*)d_out;

    char* ws = (char*)d_ws;
    u16*   hs_bf = (u16*)ws;   ws += (size_t)NROWS * DD * 2;
    u16*   WqT   = (u16*)ws;   ws += (size_t)DD * DD * 2;
    u16*   WkT   = (u16*)ws;   ws += (size_t)DD * DD * 2;   // adjacent to WqT (merged GEMM relies on this)
    u16*   WtT   = (u16*)ws;   ws += (size_t)DD * DD * 2;
    u16*   WqaT  = (u16*)ws;   ws += (size_t)HH * DD * 2;
    u16*   q_bf  = (u16*)ws;   ws += (size_t)NROWS * DD * 2;
    u16*   k_bf  = (u16*)ws;   ws += (size_t)NROWS * DD * 2;
    float* qraw  = (float*)ws; ws += QSLICE * 4 * 4;   // 4 K-split slices
    float* qksc  = (float*)ws; ws += (size_t)BB * HH * SS * 4;
    float* pq    = (float*)ws; ws += (size_t)BB * HH * 64 * 4;
    float* pk    = (float*)ws; ws += (size_t)BB * HH * 64 * 4;
    u16*   wbf   = hs_bf;  // alias: hs_bf dead after merged QK gemm, wbf written after

    int n4 = NROWS * DD / 4;
    cast_bf16_kernel<<<n4 / 256, 256, 0, stream>>>(hs, hs_bf, n4);
    transpose_cast_kernel<<<dim3(32, 32), 256, 0, stream>>>(Wq, WqT);
    transpose_cast_kernel<<<dim3(32, 32), 256, 0, stream>>>(Wk, WkT);
    transpose_cast_kernel<<<dim3(32, 32), 256, 0, stream>>>(Wt, WtT);
    wqa_transpose_kernel<<<HH * DD / 256, 256, 0, stream>>>(Wqa, WqaT);

    hipMemsetAsync(pq, 0, (size_t)BB * HH * 64 * 4, stream);
    hipMemsetAsync(pk, 0, (size_t)BB * HH * 64 * 4, stream);

    // merged Q|K GEMM: BT = WqT||WkT (2048 rows), by<4 -> q_bf, by>=4 -> k_bf
    gemm256_kernel<1><<<dim3(NROWS / 256, 8), 512, 0, stream>>>(
        hs_bf, WqT, bq, bk, nullptr, nullptr, q_bf, k_bf);

    qscore_mfma_kernel<<<dim3(NROWS / 64, 4), 256, 0, stream>>>(q_bf, WqaT, qraw);
    softmax_kernel<true><<<BB * HH, 256, 0, stream>>>(qraw, bqa, mask);
    pool_kernel<<<dim3(BB, SS / 32), 256, 0, stream>>>(qraw, q_bf, pq);
    qkscore_kernel<<<NROWS / 4, 256, 0, stream>>>(k_bf, pq, mask, qksc);
    softmax_kernel<false><<<BB * HH, 256, 0, stream>>>(qksc, nullptr, nullptr);
    pool_kernel<<<dim3(BB, SS / 32), 256, 0, stream>>>(qksc, k_bf, pk);
    weighted_kernel<<<n4 / 256, 256, 0, stream>>>(q_bf, pk, wbf);

    gemm256_kernel<2><<<dim3(NROWS / 256, 4), 512, 0, stream>>>(
        wbf, WtT, bt, nullptr, q_bf, out, nullptr, nullptr);
}

// Round 4
// 287.448 us; speedup vs baseline: 1.1604x; 1.0770x over previous
//
#include <hip/hip_runtime.h>
#include <hip/hip_bf16.h>
#include <math.h>

#define BB 8
#define SS 2048
#define DD 1024
#define HH 16
#define DHH 64
#define NROWS (BB*SS)   // 16384
#define QSLICE ((size_t)BB * HH * SS)   // elems per qscore K-split slice

typedef unsigned short u16;
typedef __attribute__((ext_vector_type(8))) __bf16 bf16x8;
typedef __attribute__((ext_vector_type(4))) float f32x4;

__device__ __forceinline__ u16 f2bf(float f) {
    union { float f; unsigned u; } v; v.f = f;
    unsigned r = v.u + 0x7fffu + ((v.u >> 16) & 1u);
    return (u16)(r >> 16);
}
__device__ __forceinline__ float bf2f(u16 b) {
    union { unsigned u; float f; } v; v.u = ((unsigned)b) << 16;
    return v.f;
}

__device__ __forceinline__ void load_lds16(const void* g, void* l) {
    __builtin_amdgcn_global_load_lds(
        (const __attribute__((address_space(1))) unsigned int*)g,
        (__attribute__((address_space(3))) unsigned int*)l,
        16, 0, 0);
}

// raw workgroup barrier WITHOUT the vmcnt(0)/lgkmcnt(0) drain __syncthreads forces.
#define BAR() do { asm volatile("" ::: "memory"); \
                   __builtin_amdgcn_s_barrier();  \
                   asm volatile("" ::: "memory"); } while (0)

// ---------------- merged prep: cast + 3 weight transposes + wqa + zero pq/pk ----
// grid ranges:
//   [0,16384)        cast hs fp32 -> bf16 (float4/thread)
//   [16384,19456)    transpose_cast Wq|Wk|Wt  (1024 blocks each)
//   [19456,19520)    WqaT
//   [19520,19536)    zero pq (2048 float4) + pk (2048 float4)
__global__ __launch_bounds__(256)
void prep_kernel(const float* __restrict__ hs, u16* __restrict__ hs_bf,
                 const float* __restrict__ Wq, u16* __restrict__ WqT,
                 const float* __restrict__ Wk, u16* __restrict__ WkT,
                 const float* __restrict__ Wt, u16* __restrict__ WtT,
                 const float* __restrict__ Wqa, u16* __restrict__ WqaT,
                 float* __restrict__ pq, float* __restrict__ pk) {
    __shared__ float tile[32][33];
    const int bid = blockIdx.x;
    const int t = threadIdx.x;
    if (bid < 16384) {
        int i = bid * 256 + t;
        float4 v = ((const float4*)hs)[i];
        ushort4 o;
        o.x = f2bf(v.x); o.y = f2bf(v.y); o.z = f2bf(v.z); o.w = f2bf(v.w);
        ((ushort4*)hs_bf)[i] = o;
        return;
    }
    if (bid < 19456) {
        int rel = bid - 16384;
        const float* W; u16* WT;
        if (rel < 1024)      { W = Wq; WT = WqT; }
        else if (rel < 2048) { W = Wk; WT = WkT; rel -= 1024; }
        else                 { W = Wt; WT = WtT; rel -= 2048; }
        int m0 = (rel & 31) * 32, k0 = (rel >> 5) * 32;
        int tx = t & 31, ty = t >> 5;
        #pragma unroll
        for (int i = 0; i < 4; i++) {
            int kk = ty + i * 8;
            tile[kk][tx] = W[(k0 + kk) * DD + m0 + tx];
        }
        __syncthreads();
        #pragma unroll
        for (int i = 0; i < 4; i++) {
            int mm = ty + i * 8;
            WT[(m0 + mm) * DD + k0 + tx] = f2bf(tile[tx][mm]);
        }
        return;
    }
    if (bid < 19520) {
        int i = (bid - 19456) * 256 + t;
        int h = i >> 10, k = i & 1023;
        WqaT[i] = f2bf(Wqa[k * HH + h]);
        return;
    }
    {
        int i = (bid - 19520) * 256 + t;          // 0..4095 float4
        float4 z = {0.f, 0.f, 0.f, 0.f};
        if (i < 2048) ((float4*)pq)[i] = z;
        else          ((float4*)pk)[i - 2048] = z;
    }
}

// ---------------- bf16 MFMA GEMM, 256x256 tile, BK=64, 8-phase schedule ----------------
// MODE 1: merged Q|K GEMM, grid (64,8): by<4 -> (bq, q_bf) + FUSED qscore partial
//         (this block's sC tile IS one 256-row x 256-k slice of q; 16 MFMA/wave vs
//         WqaT produce qraw[by][b][h][s] directly -> qscore_mfma kernel deleted);
//         by>=4 -> (bk, k_bf). bf16 C staged via LDS -> dwordx4 stores.
// MODE 2: grid (64,4). B = WtT8 + (row0>>11)<<20 (per-b pk-prescaled Wt);
//         Cf = v + bias + bf2f(res), float4 stores; res(=q_bf) read coalesced.
// OPERAND-SWAPPED MFMA in main loop: lane (m16,quad) reg r holds
//   C[row = wm*128+mi*16+m16][col = wn*64+ni*16+quad*4+r].
template<int MODE>
__global__ __launch_bounds__(512, 2)
void gemm256_kernel(const u16* __restrict__ A, const u16* __restrict__ BT,
                    const float* __restrict__ b0, const float* __restrict__ b1,
                    const u16* __restrict__ res, float* __restrict__ Cf,
                    u16* __restrict__ C0, u16* __restrict__ C1,
                    const u16* __restrict__ WqaT, float* __restrict__ qraw) {
    __shared__ u16 smem[69632];
    const int by = blockIdx.y;
    const int row0 = blockIdx.x * 256;
    const int bcol0 = by * 256;                      // column in BT row space
    const int colg0 = (MODE == 1) ? (bcol0 & 1023) : bcol0;
    const float* bias = (MODE == 1 && by >= 4) ? b1 : b0;
    u16* Cb = (MODE == 1 && by >= 4) ? C1 : C0;
    // MODE 2: select this row-band's pk-prescaled Wt copy
    const u16* BTb = (MODE == 2) ? BT + ((size_t)(row0 >> 11) << 20) : BT;

    const int t = threadIdx.x;
    const int w = t >> 6, lane = t & 63;
    const int wm = w >> 2, wn = w & 3;          // 2 x 4 wave grid
    const int m16 = lane & 15, quad = lane >> 4;

    f32x4 acc[8][4];
    #pragma unroll
    for (int i = 0; i < 8; i++)
        #pragma unroll
        for (int j = 0; j < 4; j++)
            acc[i][j] = (f32x4){0.f, 0.f, 0.f, 0.f};

    const int srow = t >> 3;                     // 0..63
    const int scol = ((t & 7) ^ (srow & 7)) * 8;
    const u16* Ag = A + (size_t)(row0 + srow) * DD + scol;
    const u16* Bg = BTb + (size_t)(bcol0 + srow) * DD + scol;

    auto STAGE_H = [&](int ktile, int mat, int half) {
        if (ktile >= 16) return;
        const int buf = ktile & 1;
        const int k0 = ktile * 64;
        const u16* g = mat ? Bg : Ag;
        u16* s = smem + mat * 32768 + buf * 16384;
        #pragma unroll
        for (int j = 0; j < 2; ++j)
            load_lds16(g + k0 + (size_t)(half * 128 + j * 64) * DD,
                       s + half * 8192 + j * 4096 + t * 8);
    };

    STAGE_H(0, 0, 0); STAGE_H(0, 0, 1); STAGE_H(0, 1, 0); STAGE_H(0, 1, 1);
    STAGE_H(1, 0, 0);
    asm volatile("s_waitcnt vmcnt(2)" ::: "memory");
    BAR();

    for (int kt = 0; kt < 16; ++kt) {
        const int cur = kt & 1;
        const u16* sAc = smem + cur * 16384;
        const u16* sBc = smem + 32768 + cur * 16384;
        bf16x8 af[4][2], bfr[4][2];

        // ---------- phase 1: read af(lo rows) + bfr(ni 0-1); stage (kt+1).A1
        #pragma unroll
        for (int mi = 0; mi < 4; ++mi)
            #pragma unroll
            for (int ks = 0; ks < 2; ++ks)
                af[mi][ks] = *(const bf16x8*)&sAc[(wm * 128 + mi * 16 + m16) * 64 +
                                                 (((ks * 4 + quad) ^ (m16 & 7)) * 8)];
        #pragma unroll
        for (int ni = 0; ni < 2; ++ni)
            #pragma unroll
            for (int ks = 0; ks < 2; ++ks)
                bfr[ni][ks] = *(const bf16x8*)&sBc[(wn * 64 + ni * 16 + m16) * 64 +
                                                   (((ks * 4 + quad) ^ (m16 & 7)) * 8)];
        STAGE_H(kt + 1, 0, 1);
        BAR();
        __builtin_amdgcn_s_setprio(1);
        #pragma unroll
        for (int mi = 0; mi < 4; ++mi)
            #pragma unroll
            for (int ni = 0; ni < 2; ++ni)
                #pragma unroll
                for (int ks = 0; ks < 2; ++ks)
                    acc[mi][ni] = __builtin_amdgcn_mfma_f32_16x16x32_bf16(
                        bfr[ni][ks], af[mi][ks], acc[mi][ni], 0, 0, 0);
        __builtin_amdgcn_s_setprio(0);
        BAR();

        // ---------- phase 2: read bfr(ni 2-3); stage (kt+1).B0
        #pragma unroll
        for (int ni = 2; ni < 4; ++ni)
            #pragma unroll
            for (int ks = 0; ks < 2; ++ks)
                bfr[ni][ks] = *(const bf16x8*)&sBc[(wn * 64 + ni * 16 + m16) * 64 +
                                                   (((ks * 4 + quad) ^ (m16 & 7)) * 8)];
        STAGE_H(kt + 1, 1, 0);
        BAR();
        __builtin_amdgcn_s_setprio(1);
        #pragma unroll
        for (int mi = 0; mi < 4; ++mi)
            #pragma unroll
            for (int ni = 2; ni < 4; ++ni)
                #pragma unroll
                for (int ks = 0; ks < 2; ++ks)
                    acc[mi][ni] = __builtin_amdgcn_mfma_f32_16x16x32_bf16(
                        bfr[ni][ks], af[mi][ks], acc[mi][ni], 0, 0, 0);
        __builtin_amdgcn_s_setprio(0);
        BAR();

        // ---------- phase 3: read af(hi rows, reuse regs); stage (kt+1).B1
        #pragma unroll
        for (int mi = 0; mi < 4; ++mi)
            #pragma unroll
            for (int ks = 0; ks < 2; ++ks)
                af[mi][ks] = *(const bf16x8*)&sAc[(wm * 128 + (4 + mi) * 16 + m16) * 64 +
                                                 (((ks * 4 + quad) ^ (m16 & 7)) * 8)];
        STAGE_H(kt + 1, 1, 1);
        BAR();
        __builtin_amdgcn_s_setprio(1);
        #pragma unroll
        for (int mi = 0; mi < 4; ++mi)
            #pragma unroll
            for (int ni = 0; ni < 2; ++ni)
                #pragma unroll
                for (int ks = 0; ks < 2; ++ks)
                    acc[4 + mi][ni] = __builtin_amdgcn_mfma_f32_16x16x32_bf16(
                        bfr[ni][ks], af[mi][ks], acc[4 + mi][ni], 0, 0, 0);
        __builtin_amdgcn_s_setprio(0);
        BAR();

        // ---------- phase 4: no reads; stage (kt+2).A0 into current buffer
        STAGE_H(kt + 2, 0, 0);
        BAR();
        __builtin_amdgcn_s_setprio(1);
        #pragma unroll
        for (int mi = 0; mi < 4; ++mi)
            #pragma unroll
            for (int ni = 2; ni < 4; ++ni)
                #pragma unroll
                for (int ks = 0; ks < 2; ++ks)
                    acc[4 + mi][ni] = __builtin_amdgcn_mfma_f32_16x16x32_bf16(
                        bfr[ni][ks], af[mi][ks], acc[4 + mi][ni], 0, 0, 0);
        __builtin_amdgcn_s_setprio(0);
        if (kt < 14) asm volatile("s_waitcnt vmcnt(2)" ::: "memory");
        else         asm volatile("s_waitcnt vmcnt(0)" ::: "memory");
        BAR();
    }

    // ---------------- epilogue ----------------
    u16* sC = smem;                               // [256][272] u16, MODE 1 only
    #pragma unroll
    for (int mi = 0; mi < 8; ++mi) {
        const int lrow = wm * 128 + mi * 16 + m16;           // 0..255 in tile
        #pragma unroll
        for (int ni = 0; ni < 4; ++ni) {
            const int lcol = wn * 64 + ni * 16 + quad * 4;   // 0..255 in tile
            const float4 bv = *(const float4*)&bias[colg0 + lcol];
            if (MODE == 1) {
                ushort4 o;
                o.x = f2bf(acc[mi][ni][0] + bv.x);
                o.y = f2bf(acc[mi][ni][1] + bv.y);
                o.z = f2bf(acc[mi][ni][2] + bv.z);
                o.w = f2bf(acc[mi][ni][3] + bv.w);
                *(ushort4*)&sC[(size_t)lrow * 272 + lcol] = o;
            } else {
                const size_t idx = (size_t)(row0 + lrow) * DD + colg0 + lcol;
                const ushort4 rv = *(const ushort4*)&res[idx];
                float4 o;
                o.x = acc[mi][ni][0] + bv.x + bf2f(rv.x);
                o.y = acc[mi][ni][1] + bv.y + bf2f(rv.y);
                o.z = acc[mi][ni][2] + bv.z + bf2f(rv.z);
                o.w = acc[mi][ni][3] + bv.w + bf2f(rv.w);
                *(float4*)&Cf[idx] = o;
            }
        }
    }
    if (MODE == 1) {
        __syncthreads();
        #pragma unroll
        for (int it = 0; it < 16; ++it) {
            const int r = it * 16 + (t >> 5);
            const int c = t & 31;
            uint4 v = *(const uint4*)&sC[(size_t)r * 272 + c * 8];
            *(uint4*)&Cb[(size_t)(row0 + r) * DD + colg0 + c * 8] = v;
        }
        // ---- fused qscore partial: qraw[by][b][h][s] from this block's sC ----
        if (by < 4) {
            const int bIdx = row0 >> 11;            // constant per block
            bf16x8 wq[8];
            const u16* bp = WqaT + (size_t)m16 * DD + by * 256 + quad * 8;
            #pragma unroll
            for (int kk = 0; kk < 8; ++kk) wq[kk] = *(const bf16x8*)(bp + kk * 32);
            #pragma unroll
            for (int rt = 0; rt < 2; ++rt) {
                const int sr = (w * 2 + rt) * 16;   // 16 row-tiles over 8 waves
                f32x4 qa = (f32x4){0.f, 0.f, 0.f, 0.f};
                #pragma unroll
                for (int kk = 0; kk < 8; ++kk) {
                    bf16x8 a = *(const bf16x8*)&sC[(size_t)(sr + m16) * 272 + quad * 8 + kk * 32];
                    qa = __builtin_amdgcn_mfma_f32_16x16x32_bf16(a, wq[kk], qa, 0, 0, 0);
                }
                #pragma unroll
                for (int r = 0; r < 4; ++r) {
                    int s = (row0 & 2047) + sr + quad * 4 + r;
                    qraw[((size_t)(by * BB + bIdx) * HH + m16) * SS + s] = qa[r];
                }
            }
        }
    }
}

// ---------------- WtT8[b][n][k] = bf16( WtT[n][k] * pk[b][k] ) ----------------
// grid = 4096 x 256: thread handles 8 contiguous k.
__global__ __launch_bounds__(256)
void wtscale_kernel(const u16* __restrict__ WtT, const float* __restrict__ pk,
                    u16* __restrict__ WtT8) {
    size_t i = (size_t)blockIdx.x * 256 + threadIdx.x;   // < 1048576
    int b = (int)(i >> 17);
    size_t off = (i & 131071) << 3;                      // elem offset within Wt
    int d = (int)(off & 1023);
    const float4 p0 = *(const float4*)&pk[b * 1024 + d];
    const float4 p1 = *(const float4*)&pk[b * 1024 + d + 4];
    ushort4 a0 = ((const ushort4*)(WtT + off))[0];
    ushort4 a1 = ((const ushort4*)(WtT + off))[1];
    ushort4 o0, o1;
    o0.x = f2bf(bf2f(a0.x) * p0.x); o0.y = f2bf(bf2f(a0.y) * p0.y);
    o0.z = f2bf(bf2f(a0.z) * p0.z); o0.w = f2bf(bf2f(a0.w) * p0.w);
    o1.x = f2bf(bf2f(a1.x) * p1.x); o1.y = f2bf(bf2f(a1.y) * p1.y);
    o1.z = f2bf(bf2f(a1.z) * p1.z); o1.w = f2bf(bf2f(a1.w) * p1.w);
    u16* dst = WtT8 + ((size_t)b << 20) + off;
    ((ushort4*)dst)[0] = o0;
    ((ushort4*)dst)[1] = o1;
}

// ---------------- softmax over S, writes slice 0 ----------------
template<bool EPI>
__global__ __launch_bounds__(256)
void softmax_kernel(float* __restrict__ score, const float* __restrict__ bqa,
                    const float* __restrict__ mask) {
    int bh = blockIdx.x;
    int b = bh >> 4, h = bh & 15;
    float* srow = score + ((size_t)bh << 11);
    __shared__ float rm[4], rs[4];
    int t = threadIdx.x;

    float v[8];
    float m = -1e30f;
    #pragma unroll
    for (int i = 0; i < 8; i++) {
        int off = t + i * 256;
        float x;
        if (EPI) {
            x = srow[off] + srow[off + QSLICE] + srow[off + 2 * QSLICE] + srow[off + 3 * QSLICE];
            x = (x + bqa[h]) * 0.125f + mask[b * SS + off];
        } else {
            x = srow[off];
        }
        v[i] = x; m = fmaxf(m, x);
    }
    #pragma unroll
    for (int off = 32; off; off >>= 1) m = fmaxf(m, __shfl_xor(m, off));
    if ((t & 63) == 0) rm[t >> 6] = m;
    __syncthreads();
    m = fmaxf(fmaxf(rm[0], rm[1]), fmaxf(rm[2], rm[3]));

    float sum = 0.f;
    #pragma unroll
    for (int i = 0; i < 8; i++) { v[i] = __expf(v[i] - m); sum += v[i]; }
    #pragma unroll
    for (int off = 32; off; off >>= 1) sum += __shfl_xor(sum, off);
    if ((t & 63) == 0) rs[t >> 6] = sum;
    __syncthreads();
    float inv = 1.0f / (rs[0] + rs[1] + rs[2] + rs[3]);
    #pragma unroll
    for (int i = 0; i < 8; i++) srow[t + i * 256] = v[i] * inv;
}

// ---------------- pooled[b,:,:] += sum_{s in 32-chunk} w[b,h,s] * X[b,s,:] ----------------
__global__ __launch_bounds__(256)
void pool_kernel(const float* __restrict__ w, const u16* __restrict__ X,
                 float* __restrict__ pooled) {
    int b = blockIdx.x;
    int s0 = blockIdx.y * 32;
    int t = threadIdx.x;
    int wid = t >> 6, lane = t & 63;
    int h = lane >> 2;
    __shared__ float sw[16 * 33];
    __shared__ float pr[4][64 * 17];
    {
        int hh = t >> 4, si = t & 15;
        const float* wr = w + ((size_t)(b * HH + hh) << 11) + s0;
        sw[hh * 33 + si] = wr[si];
        sw[hh * 33 + si + 16] = wr[si + 16];
    }
    __syncthreads();
    float acc[16];
    #pragma unroll
    for (int j = 0; j < 16; j++) acc[j] = 0.f;
    const u16* xbase = X + ((size_t)(b * SS + s0 + wid * 8) << 10) + lane * 16;
    #pragma unroll
    for (int rr = 0; rr < 8; rr++) {
        float ws = sw[h * 33 + wid * 8 + rr];
        const uint4* xp = (const uint4*)(xbase + (size_t)rr * DD);
        uint4 x0 = xp[0], x1 = xp[1];
        unsigned xw[8] = {x0.x, x0.y, x0.z, x0.w, x1.x, x1.y, x1.z, x1.w};
        #pragma unroll
        for (int i2 = 0; i2 < 8; i2++) {
            union { unsigned u; float f; } lo, hi;
            lo.u = xw[i2] << 16; hi.u = xw[i2] & 0xffff0000u;
            acc[2 * i2]     += ws * lo.f;
            acc[2 * i2 + 1] += ws * hi.f;
        }
    }
    #pragma unroll
    for (int j = 0; j < 16; j++) pr[wid][lane * 17 + j] = acc[j];
    __syncthreads();
    #pragma unroll
    for (int i = 0; i < 4; i++) {
        int idx = t + i * 256;                       // 0..1023 = lane'*16 + j
        int l2 = idx >> 4, j2 = idx & 15;
        float v = pr[0][l2 * 17 + j2] + pr[1][l2 * 17 + j2] +
                  pr[2][l2 * 17 + j2] + pr[3][l2 * 17 + j2];
        int od = (l2 >> 2) * 64 + (l2 & 3) * 16 + j2;  // h*64 + d
        atomicAdd(&pooled[b * DD + od], v);
    }
}

// ---------------- qk_score[b,h,s] = (k[b,s,h*64:]·pq[b,h,:])*scale + mask ----------------
__global__ __launch_bounds__(256)
void qkscore_kernel(const u16* __restrict__ kbf, const float* __restrict__ pq,
                    const float* __restrict__ mask, float* __restrict__ qkscore) {
    int row = blockIdx.x * 4 + (threadIdx.x >> 6);
    int lane = threadIdx.x & 63;
    int b = row >> 11, s = row & 2047;
    int h = lane >> 2, dp = lane & 3;
    const u16* kp = kbf + (size_t)row * DD + h * 64 + dp * 16;
    const float* pqp = pq + (size_t)(b * HH + h) * 64 + dp * 16;
    const uint4* kp4 = (const uint4*)kp;
    uint4 ka = kp4[0], kb4 = kp4[1];
    unsigned kw[8] = {ka.x, ka.y, ka.z, ka.w, kb4.x, kb4.y, kb4.z, kb4.w};
    float acc = 0.f;
    #pragma unroll
    for (int i = 0; i < 8; i++) {
        union { unsigned u; float f; } lo, hi;
        lo.u = kw[i] << 16;
        hi.u = kw[i] & 0xffff0000u;
        acc += lo.f * pqp[2 * i] + hi.f * pqp[2 * i + 1];
    }
    acc += __shfl_xor(acc, 1);
    acc += __shfl_xor(acc, 2);
    if (dp == 0) qkscore[(size_t)(b * HH + h) * SS + s] = acc * 0.125f + mask[b * SS + s];
}

extern "C" void kernel_launch(void* const* d_in, const int* in_sizes, int n_in,
                              void* d_out, int out_size, void* d_ws, size_t ws_size,
                              hipStream_t stream) {
    const float* hs   = (const float*)d_in[0];
    const float* mask = (const float*)d_in[1];
    const float* Wq   = (const float*)d_in[2];
    const float* bq   = (const float*)d_in[3];
    const float* Wqa  = (const float*)d_in[4];
    const float* bqa  = (const float*)d_in[5];
    const float* Wk   = (const float*)d_in[6];
    const float* bk   = (const float*)d_in[7];
    const float* Wt   = (const float*)d_in[8];
    const float* bt   = (const float*)d_in[9];
    float* out = (float*)d_out;

    char* ws = (char*)d_ws;
    u16*   hs_bf = (u16*)ws;   ws += (size_t)NROWS * DD * 2;
    u16*   WqT   = (u16*)ws;   ws += (size_t)DD * DD * 2;
    u16*   WkT   = (u16*)ws;   ws += (size_t)DD * DD * 2;   // adjacent to WqT (merged GEMM)
    u16*   WtT   = (u16*)ws;   ws += (size_t)DD * DD * 2;
    u16*   WqaT  = (u16*)ws;   ws += (size_t)HH * DD * 2;
    u16*   q_bf  = (u16*)ws;   ws += (size_t)NROWS * DD * 2;
    u16*   k_bf  = (u16*)ws;   ws += (size_t)NROWS * DD * 2;
    float* qraw  = (float*)ws; ws += QSLICE * 4 * 4;   // 4 K-split slices
    float* qksc  = (float*)ws; ws += (size_t)BB * HH * SS * 4;
    float* pq    = (float*)ws; ws += (size_t)BB * HH * 64 * 4;
    float* pk    = (float*)ws; ws += (size_t)BB * HH * 64 * 4;
    u16*   WtT8  = hs_bf;  // alias: hs_bf (32 MiB) dead after merged QK gemm; WtT8 = 16 MiB

    prep_kernel<<<19536, 256, 0, stream>>>(hs, hs_bf, Wq, WqT, Wk, WkT, Wt, WtT,
                                           Wqa, WqaT, pq, pk);

    // merged Q|K GEMM (+fused qscore partials on by<4): BT = WqT||WkT (2048 rows)
    gemm256_kernel<1><<<dim3(NROWS / 256, 8), 512, 0, stream>>>(
        hs_bf, WqT, bq, bk, nullptr, nullptr, q_bf, k_bf, WqaT, qraw);

    softmax_kernel<true><<<BB * HH, 256, 0, stream>>>(qraw, bqa, mask);
    pool_kernel<<<dim3(BB, SS / 32), 256, 0, stream>>>(qraw, q_bf, pq);
    qkscore_kernel<<<NROWS / 4, 256, 0, stream>>>(k_bf, pq, mask, qksc);
    softmax_kernel<false><<<BB * HH, 256, 0, stream>>>(qksc, nullptr, nullptr);
    pool_kernel<<<dim3(BB, SS / 32), 256, 0, stream>>>(qksc, k_bf, pk);
    wtscale_kernel<<<4096, 256, 0, stream>>>(WtT, pk, WtT8);

    // out = q_bf @ (pk-scaled Wt)^T + bt + q_bf   (res == A, shared fetch)
    gemm256_kernel<2><<<dim3(NROWS / 256, 4), 512, 0, stream>>>(
        q_bf, WtT8, bt, nullptr, q_bf, out, nullptr, nullptr, nullptr, nullptr);
}

// Round 5
// 285.054 us; speedup vs baseline: 1.1702x; 1.0084x over previous
//
#include <hip/hip_runtime.h>
#include <hip/hip_bf16.h>
#include <math.h>

#define BB 8
#define SS 2048
#define DD 1024
#define HH 16
#define DHH 64
#define NROWS (BB*SS)   // 16384
#define QSLICE ((size_t)BB * HH * SS)   // elems per qscore K-split slice

typedef unsigned short u16;
typedef __attribute__((ext_vector_type(8))) __bf16 bf16x8;
typedef __attribute__((ext_vector_type(4))) float f32x4;

__device__ __forceinline__ u16 f2bf(float f) {
    union { float f; unsigned u; } v; v.f = f;
    unsigned r = v.u + 0x7fffu + ((v.u >> 16) & 1u);
    return (u16)(r >> 16);
}
__device__ __forceinline__ float bf2f(u16 b) {
    union { unsigned u; float f; } v; v.u = ((unsigned)b) << 16;
    return v.f;
}

__device__ __forceinline__ void load_lds16(const void* g, void* l) {
    __builtin_amdgcn_global_load_lds(
        (const __attribute__((address_space(1))) unsigned int*)g,
        (__attribute__((address_space(3))) unsigned int*)l,
        16, 0, 0);
}

// raw workgroup barrier WITHOUT the vmcnt(0)/lgkmcnt(0) drain __syncthreads forces.
#define BAR() do { asm volatile("" ::: "memory"); \
                   __builtin_amdgcn_s_barrier();  \
                   asm volatile("" ::: "memory"); } while (0)

// ---------------- merged prep: cast + 3 weight transposes + wqa ----------------
// grid ranges:
//   [0,16384)        cast hs fp32 -> bf16 (float4/thread)
//   [16384,19456)    transpose_cast Wq|Wk|Wt  (1024 blocks each)
//   [19456,19520)    WqaT
__global__ __launch_bounds__(256)
void prep_kernel(const float* __restrict__ hs, u16* __restrict__ hs_bf,
                 const float* __restrict__ Wq, u16* __restrict__ WqT,
                 const float* __restrict__ Wk, u16* __restrict__ WkT,
                 const float* __restrict__ Wt, u16* __restrict__ WtT,
                 const float* __restrict__ Wqa, u16* __restrict__ WqaT) {
    __shared__ float tile[32][33];
    const int bid = blockIdx.x;
    const int t = threadIdx.x;
    if (bid < 16384) {
        int i = bid * 256 + t;
        float4 v = ((const float4*)hs)[i];
        ushort4 o;
        o.x = f2bf(v.x); o.y = f2bf(v.y); o.z = f2bf(v.z); o.w = f2bf(v.w);
        ((ushort4*)hs_bf)[i] = o;
        return;
    }
    if (bid < 19456) {
        int rel = bid - 16384;
        const float* W; u16* WT;
        if (rel < 1024)      { W = Wq; WT = WqT; }
        else if (rel < 2048) { W = Wk; WT = WkT; rel -= 1024; }
        else                 { W = Wt; WT = WtT; rel -= 2048; }
        int m0 = (rel & 31) * 32, k0 = (rel >> 5) * 32;
        int tx = t & 31, ty = t >> 5;
        #pragma unroll
        for (int i = 0; i < 4; i++) {
            int kk = ty + i * 8;
            tile[kk][tx] = W[(k0 + kk) * DD + m0 + tx];
        }
        __syncthreads();
        #pragma unroll
        for (int i = 0; i < 4; i++) {
            int mm = ty + i * 8;
            WT[(m0 + mm) * DD + k0 + tx] = f2bf(tile[tx][mm]);
        }
        return;
    }
    {
        int i = (bid - 19456) * 256 + t;
        int h = i >> 10, k = i & 1023;
        WqaT[i] = f2bf(Wqa[k * HH + h]);
    }
}

// ---------------- bf16 MFMA GEMM, 256x256 tile, BK=64, 8-phase schedule ----------------
// MODE 1: merged Q|K GEMM, grid (64,8): by<4 -> (bq, q_bf) + FUSED qscore partial;
//         by>=4 -> (bk, k_bf). bf16 C staged via LDS -> dwordx4 stores.
// MODE 2: grid (64,4). B = WtT8 + (row0>>11)<<20 (per-b pk-prescaled Wt);
//         Cf = v + bias + bf2f(res), float4 stores.
// OPERAND-SWAPPED MFMA: lane (m16,quad) reg r = C[wm*128+mi*16+m16][wn*64+ni*16+quad*4+r].
template<int MODE>
__global__ __launch_bounds__(512, 2)
void gemm256_kernel(const u16* __restrict__ A, const u16* __restrict__ BT,
                    const float* __restrict__ b0, const float* __restrict__ b1,
                    const u16* __restrict__ res, float* __restrict__ Cf,
                    u16* __restrict__ C0, u16* __restrict__ C1,
                    const u16* __restrict__ WqaT, float* __restrict__ qraw) {
    __shared__ u16 smem[69632];
    const int by = blockIdx.y;
    const int row0 = blockIdx.x * 256;
    const int bcol0 = by * 256;                      // column in BT row space
    const int colg0 = (MODE == 1) ? (bcol0 & 1023) : bcol0;
    const float* bias = (MODE == 1 && by >= 4) ? b1 : b0;
    u16* Cb = (MODE == 1 && by >= 4) ? C1 : C0;
    const u16* BTb = (MODE == 2) ? BT + ((size_t)(row0 >> 11) << 20) : BT;

    const int t = threadIdx.x;
    const int w = t >> 6, lane = t & 63;
    const int wm = w >> 2, wn = w & 3;          // 2 x 4 wave grid
    const int m16 = lane & 15, quad = lane >> 4;

    f32x4 acc[8][4];
    #pragma unroll
    for (int i = 0; i < 8; i++)
        #pragma unroll
        for (int j = 0; j < 4; j++)
            acc[i][j] = (f32x4){0.f, 0.f, 0.f, 0.f};

    const int srow = t >> 3;                     // 0..63
    const int scol = ((t & 7) ^ (srow & 7)) * 8;
    const u16* Ag = A + (size_t)(row0 + srow) * DD + scol;
    const u16* Bg = BTb + (size_t)(bcol0 + srow) * DD + scol;

    auto STAGE_H = [&](int ktile, int mat, int half) {
        if (ktile >= 16) return;
        const int buf = ktile & 1;
        const int k0 = ktile * 64;
        const u16* g = mat ? Bg : Ag;
        u16* s = smem + mat * 32768 + buf * 16384;
        #pragma unroll
        for (int j = 0; j < 2; ++j)
            load_lds16(g + k0 + (size_t)(half * 128 + j * 64) * DD,
                       s + half * 8192 + j * 4096 + t * 8);
    };

    STAGE_H(0, 0, 0); STAGE_H(0, 0, 1); STAGE_H(0, 1, 0); STAGE_H(0, 1, 1);
    STAGE_H(1, 0, 0);
    asm volatile("s_waitcnt vmcnt(2)" ::: "memory");
    BAR();

    for (int kt = 0; kt < 16; ++kt) {
        const int cur = kt & 1;
        const u16* sAc = smem + cur * 16384;
        const u16* sBc = smem + 32768 + cur * 16384;
        bf16x8 af[4][2], bfr[4][2];

        // ---------- phase 1: read af(lo rows) + bfr(ni 0-1); stage (kt+1).A1
        #pragma unroll
        for (int mi = 0; mi < 4; ++mi)
            #pragma unroll
            for (int ks = 0; ks < 2; ++ks)
                af[mi][ks] = *(const bf16x8*)&sAc[(wm * 128 + mi * 16 + m16) * 64 +
                                                 (((ks * 4 + quad) ^ (m16 & 7)) * 8)];
        #pragma unroll
        for (int ni = 0; ni < 2; ++ni)
            #pragma unroll
            for (int ks = 0; ks < 2; ++ks)
                bfr[ni][ks] = *(const bf16x8*)&sBc[(wn * 64 + ni * 16 + m16) * 64 +
                                                   (((ks * 4 + quad) ^ (m16 & 7)) * 8)];
        STAGE_H(kt + 1, 0, 1);
        BAR();
        __builtin_amdgcn_s_setprio(1);
        #pragma unroll
        for (int mi = 0; mi < 4; ++mi)
            #pragma unroll
            for (int ni = 0; ni < 2; ++ni)
                #pragma unroll
                for (int ks = 0; ks < 2; ++ks)
                    acc[mi][ni] = __builtin_amdgcn_mfma_f32_16x16x32_bf16(
                        bfr[ni][ks], af[mi][ks], acc[mi][ni], 0, 0, 0);
        __builtin_amdgcn_s_setprio(0);
        BAR();

        // ---------- phase 2: read bfr(ni 2-3); stage (kt+1).B0
        #pragma unroll
        for (int ni = 2; ni < 4; ++ni)
            #pragma unroll
            for (int ks = 0; ks < 2; ++ks)
                bfr[ni][ks] = *(const bf16x8*)&sBc[(wn * 64 + ni * 16 + m16) * 64 +
                                                   (((ks * 4 + quad) ^ (m16 & 7)) * 8)];
        STAGE_H(kt + 1, 1, 0);
        BAR();
        __builtin_amdgcn_s_setprio(1);
        #pragma unroll
        for (int mi = 0; mi < 4; ++mi)
            #pragma unroll
            for (int ni = 2; ni < 4; ++ni)
                #pragma unroll
                for (int ks = 0; ks < 2; ++ks)
                    acc[mi][ni] = __builtin_amdgcn_mfma_f32_16x16x32_bf16(
                        bfr[ni][ks], af[mi][ks], acc[mi][ni], 0, 0, 0);
        __builtin_amdgcn_s_setprio(0);
        BAR();

        // ---------- phase 3: read af(hi rows, reuse regs); stage (kt+1).B1
        #pragma unroll
        for (int mi = 0; mi < 4; ++mi)
            #pragma unroll
            for (int ks = 0; ks < 2; ++ks)
                af[mi][ks] = *(const bf16x8*)&sAc[(wm * 128 + (4 + mi) * 16 + m16) * 64 +
                                                 (((ks * 4 + quad) ^ (m16 & 7)) * 8)];
        STAGE_H(kt + 1, 1, 1);
        BAR();
        __builtin_amdgcn_s_setprio(1);
        #pragma unroll
        for (int mi = 0; mi < 4; ++mi)
            #pragma unroll
            for (int ni = 0; ni < 2; ++ni)
                #pragma unroll
                for (int ks = 0; ks < 2; ++ks)
                    acc[4 + mi][ni] = __builtin_amdgcn_mfma_f32_16x16x32_bf16(
                        bfr[ni][ks], af[mi][ks], acc[4 + mi][ni], 0, 0, 0);
        __builtin_amdgcn_s_setprio(0);
        BAR();

        // ---------- phase 4: no reads; stage (kt+2).A0 into current buffer
        STAGE_H(kt + 2, 0, 0);
        BAR();
        __builtin_amdgcn_s_setprio(1);
        #pragma unroll
        for (int mi = 0; mi < 4; ++mi)
            #pragma unroll
            for (int ni = 2; ni < 4; ++ni)
                #pragma unroll
                for (int ks = 0; ks < 2; ++ks)
                    acc[4 + mi][ni] = __builtin_amdgcn_mfma_f32_16x16x32_bf16(
                        bfr[ni][ks], af[mi][ks], acc[4 + mi][ni], 0, 0, 0);
        __builtin_amdgcn_s_setprio(0);
        if (kt < 14) asm volatile("s_waitcnt vmcnt(2)" ::: "memory");
        else         asm volatile("s_waitcnt vmcnt(0)" ::: "memory");
        BAR();
    }

    // ---------------- epilogue ----------------
    u16* sC = smem;                               // [256][272] u16, MODE 1 only
    #pragma unroll
    for (int mi = 0; mi < 8; ++mi) {
        const int lrow = wm * 128 + mi * 16 + m16;           // 0..255 in tile
        #pragma unroll
        for (int ni = 0; ni < 4; ++ni) {
            const int lcol = wn * 64 + ni * 16 + quad * 4;   // 0..255 in tile
            const float4 bv = *(const float4*)&bias[colg0 + lcol];
            if (MODE == 1) {
                ushort4 o;
                o.x = f2bf(acc[mi][ni][0] + bv.x);
                o.y = f2bf(acc[mi][ni][1] + bv.y);
                o.z = f2bf(acc[mi][ni][2] + bv.z);
                o.w = f2bf(acc[mi][ni][3] + bv.w);
                *(ushort4*)&sC[(size_t)lrow * 272 + lcol] = o;
            } else {
                const size_t idx = (size_t)(row0 + lrow) * DD + colg0 + lcol;
                const ushort4 rv = *(const ushort4*)&res[idx];
                float4 o;
                o.x = acc[mi][ni][0] + bv.x + bf2f(rv.x);
                o.y = acc[mi][ni][1] + bv.y + bf2f(rv.y);
                o.z = acc[mi][ni][2] + bv.z + bf2f(rv.z);
                o.w = acc[mi][ni][3] + bv.w + bf2f(rv.w);
                *(float4*)&Cf[idx] = o;
            }
        }
    }
    if (MODE == 1) {
        __syncthreads();
        #pragma unroll
        for (int it = 0; it < 16; ++it) {
            const int r = it * 16 + (t >> 5);
            const int c = t & 31;
            uint4 v = *(const uint4*)&sC[(size_t)r * 272 + c * 8];
            *(uint4*)&Cb[(size_t)(row0 + r) * DD + colg0 + c * 8] = v;
        }
        // ---- fused qscore partial: qraw[by][b][h][s] from this block's sC ----
        if (by < 4) {
            const int bIdx = row0 >> 11;
            bf16x8 wq[8];
            const u16* bp = WqaT + (size_t)m16 * DD + by * 256 + quad * 8;
            #pragma unroll
            for (int kk = 0; kk < 8; ++kk) wq[kk] = *(const bf16x8*)(bp + kk * 32);
            #pragma unroll
            for (int rt = 0; rt < 2; ++rt) {
                const int sr = (w * 2 + rt) * 16;
                f32x4 qa = (f32x4){0.f, 0.f, 0.f, 0.f};
                #pragma unroll
                for (int kk = 0; kk < 8; ++kk) {
                    bf16x8 a = *(const bf16x8*)&sC[(size_t)(sr + m16) * 272 + quad * 8 + kk * 32];
                    qa = __builtin_amdgcn_mfma_f32_16x16x32_bf16(a, wq[kk], qa, 0, 0, 0);
                }
                #pragma unroll
                for (int r = 0; r < 4; ++r) {
                    int s = (row0 & 2047) + sr + quad * 4 + r;
                    qraw[((size_t)(by * BB + bIdx) * HH + m16) * SS + s] = qa[r];
                }
            }
        }
    }
}

// ---------------- fused middle: softmax(qscore) -> pool q -> qkscore -> softmax -> pool k
// one block per (b,h), 512 threads (8 waves). pq lives in LDS only; pk written direct.
__global__ __launch_bounds__(512)
void attnmid_kernel(const float* __restrict__ qraw, const float* __restrict__ bqa,
                    const float* __restrict__ mask, const u16* __restrict__ qbf,
                    const u16* __restrict__ kbf, float* __restrict__ pk) {
    const int bh = blockIdx.x;
    const int b = bh >> 4, h = bh & 15;
    const int t = threadIdx.x;
    const int wid = t >> 6, lane = t & 63;
    __shared__ float sw[SS];        // row weights (8 KB)
    __shared__ float red[8];        // per-wave scalar reduce
    __shared__ float prr[8][64];    // pool partials per wave
    __shared__ float pql[64];       // pooled_q for this (b,h)

    // ---- phase 1: softmax of q attention logits ----
    {
        const float* qr = qraw + ((size_t)bh << 11);
        float v[4]; float m = -1e30f;
        #pragma unroll
        for (int i = 0; i < 4; i++) {
            int off = t + i * 512;
            float x = qr[off] + qr[off + QSLICE] + qr[off + 2 * QSLICE] + qr[off + 3 * QSLICE];
            x = (x + bqa[h]) * 0.125f + mask[b * SS + off];
            v[i] = x; m = fmaxf(m, x);
        }
        #pragma unroll
        for (int o = 32; o; o >>= 1) m = fmaxf(m, __shfl_xor(m, o));
        if (lane == 0) red[wid] = m;
        __syncthreads();
        m = red[0];
        #pragma unroll
        for (int i = 1; i < 8; i++) m = fmaxf(m, red[i]);
        float sum = 0.f;
        #pragma unroll
        for (int i = 0; i < 4; i++) { v[i] = __expf(v[i] - m); sum += v[i]; }
        #pragma unroll
        for (int o = 32; o; o >>= 1) sum += __shfl_xor(sum, o);
        __syncthreads();
        if (lane == 0) red[wid] = sum;
        __syncthreads();
        float tot = 0.f;
        #pragma unroll
        for (int i = 0; i < 8; i++) tot += red[i];
        float inv = 1.0f / tot;
        #pragma unroll
        for (int i = 0; i < 4; i++) sw[t + i * 512] = v[i] * inv;
        __syncthreads();
    }

    // ---- phase 2: pool q -> pql[64] (wave wid covers s in [wid*256, wid*256+256)) ----
    {
        const int d0 = (lane & 31) * 2;
        const int srel = lane >> 5;
        const u16* base = qbf + (((size_t)b * SS) << 10) + h * 64 + d0;
        float a0 = 0.f, a1 = 0.f;
        #pragma unroll 8
        for (int it = 0; it < 128; ++it) {
            int s = wid * 256 + it * 2 + srel;
            unsigned kw = *(const unsigned*)(base + ((size_t)s << 10));
            float wf = sw[s];
            union { unsigned u; float f; } lo, hi;
            lo.u = kw << 16; hi.u = kw & 0xffff0000u;
            a0 += wf * lo.f; a1 += wf * hi.f;
        }
        a0 += __shfl_xor(a0, 32); a1 += __shfl_xor(a1, 32);
        if (lane < 32) { prr[wid][d0] = a0; prr[wid][d0 + 1] = a1; }
        __syncthreads();
        if (t < 64) {
            float s2 = 0.f;
            #pragma unroll
            for (int w2 = 0; w2 < 8; w2++) s2 += prr[w2][t];
            pql[t] = s2;
        }
        __syncthreads();
    }

    // ---- phase 3: qk score + softmax -> sw ----
    {
        float v[4]; float m = -1e30f;
        #pragma unroll
        for (int i = 0; i < 4; i++) {
            int s = t + i * 512;
            const uint4* kp = (const uint4*)(kbf + (((size_t)(b * SS + s)) << 10) + h * 64);
            float acc = 0.f;
            #pragma unroll
            for (int j = 0; j < 8; j++) {
                uint4 kv = kp[j];
                unsigned ww[4] = {kv.x, kv.y, kv.z, kv.w};
                #pragma unroll
                for (int q2 = 0; q2 < 4; q2++) {
                    union { unsigned u; float f; } lo, hi;
                    lo.u = ww[q2] << 16; hi.u = ww[q2] & 0xffff0000u;
                    acc += lo.f * pql[j * 8 + q2 * 2] + hi.f * pql[j * 8 + q2 * 2 + 1];
                }
            }
            float x = acc * 0.125f + mask[b * SS + s];
            v[i] = x; m = fmaxf(m, x);
        }
        #pragma unroll
        for (int o = 32; o; o >>= 1) m = fmaxf(m, __shfl_xor(m, o));
        __syncthreads();                   // sw reads of phase 2 done; red free
        if (lane == 0) red[wid] = m;
        __syncthreads();
        m = red[0];
        #pragma unroll
        for (int i = 1; i < 8; i++) m = fmaxf(m, red[i]);
        float sum = 0.f;
        #pragma unroll
        for (int i = 0; i < 4; i++) { v[i] = __expf(v[i] - m); sum += v[i]; }
        #pragma unroll
        for (int o = 32; o; o >>= 1) sum += __shfl_xor(sum, o);
        __syncthreads();
        if (lane == 0) red[wid] = sum;
        __syncthreads();
        float tot = 0.f;
        #pragma unroll
        for (int i = 0; i < 8; i++) tot += red[i];
        float inv = 1.0f / tot;
        #pragma unroll
        for (int i = 0; i < 4; i++) sw[t + i * 512] = v[i] * inv;
        __syncthreads();
    }

    // ---- phase 4: pool k -> pk[b, h*64 + d] ----
    {
        const int d0 = (lane & 31) * 2;
        const int srel = lane >> 5;
        const u16* base = kbf + (((size_t)b * SS) << 10) + h * 64 + d0;
        float a0 = 0.f, a1 = 0.f;
        #pragma unroll 8
        for (int it = 0; it < 128; ++it) {
            int s = wid * 256 + it * 2 + srel;
            unsigned kw = *(const unsigned*)(base + ((size_t)s << 10));
            float wf = sw[s];
            union { unsigned u; float f; } lo, hi;
            lo.u = kw << 16; hi.u = kw & 0xffff0000u;
            a0 += wf * lo.f; a1 += wf * hi.f;
        }
        a0 += __shfl_xor(a0, 32); a1 += __shfl_xor(a1, 32);
        if (lane < 32) { prr[wid][d0] = a0; prr[wid][d0 + 1] = a1; }
        __syncthreads();
        if (t < 64) {
            float s2 = 0.f;
            #pragma unroll
            for (int w2 = 0; w2 < 8; w2++) s2 += prr[w2][t];
            pk[b * DD + h * 64 + t] = s2;
        }
    }
}

// ---------------- WtT8[b][n][k] = bf16( WtT[n][k] * pk[b][k] ) ----------------
__global__ __launch_bounds__(256)
void wtscale_kernel(const u16* __restrict__ WtT, const float* __restrict__ pk,
                    u16* __restrict__ WtT8) {
    size_t i = (size_t)blockIdx.x * 256 + threadIdx.x;   // < 1048576
    int b = (int)(i >> 17);
    size_t off = (i & 131071) << 3;                      // elem offset within Wt
    int d = (int)(off & 1023);
    const float4 p0 = *(const float4*)&pk[b * 1024 + d];
    const float4 p1 = *(const float4*)&pk[b * 1024 + d + 4];
    ushort4 a0 = ((const ushort4*)(WtT + off))[0];
    ushort4 a1 = ((const ushort4*)(WtT + off))[1];
    ushort4 o0, o1;
    o0.x = f2bf(bf2f(a0.x) * p0.x); o0.y = f2bf(bf2f(a0.y) * p0.y);
    o0.z = f2bf(bf2f(a0.z) * p0.z); o0.w = f2bf(bf2f(a0.w) * p0.w);
    o1.x = f2bf(bf2f(a1.x) * p1.x); o1.y = f2bf(bf2f(a1.y) * p1.y);
    o1.z = f2bf(bf2f(a1.z) * p1.z); o1.w = f2bf(bf2f(a1.w) * p1.w);
    u16* dst = WtT8 + ((size_t)b << 20) + off;
    ((ushort4*)dst)[0] = o0;
    ((ushort4*)dst)[1] = o1;
}

extern "C" void kernel_launch(void* const* d_in, const int* in_sizes, int n_in,
                              void* d_out, int out_size, void* d_ws, size_t ws_size,
                              hipStream_t stream) {
    const float* hs   = (const float*)d_in[0];
    const float* mask = (const float*)d_in[1];
    const float* Wq   = (const float*)d_in[2];
    const float* bq   = (const float*)d_in[3];
    const float* Wqa  = (const float*)d_in[4];
    const float* bqa  = (const float*)d_in[5];
    const float* Wk   = (const float*)d_in[6];
    const float* bk   = (const float*)d_in[7];
    const float* Wt   = (const float*)d_in[8];
    const float* bt   = (const float*)d_in[9];
    float* out = (float*)d_out;

    char* ws = (char*)d_ws;
    u16*   hs_bf = (u16*)ws;   ws += (size_t)NROWS * DD * 2;
    u16*   WqT   = (u16*)ws;   ws += (size_t)DD * DD * 2;
    u16*   WkT   = (u16*)ws;   ws += (size_t)DD * DD * 2;   // adjacent to WqT (merged GEMM)
    u16*   WtT   = (u16*)ws;   ws += (size_t)DD * DD * 2;
    u16*   WqaT  = (u16*)ws;   ws += (size_t)HH * DD * 2;
    u16*   q_bf  = (u16*)ws;   ws += (size_t)NROWS * DD * 2;
    u16*   k_bf  = (u16*)ws;   ws += (size_t)NROWS * DD * 2;
    float* qraw  = (float*)ws; ws += QSLICE * 4 * 4;   // 4 K-split slices
    float* pk    = (float*)ws; ws += (size_t)BB * HH * 64 * 4;
    u16*   WtT8  = hs_bf;  // alias: hs_bf (32 MiB) dead after merged QK gemm; WtT8 = 16 MiB

    prep_kernel<<<19520, 256, 0, stream>>>(hs, hs_bf, Wq, WqT, Wk, WkT, Wt, WtT,
                                           Wqa, WqaT);

    // merged Q|K GEMM (+fused qscore partials on by<4): BT = WqT||WkT (2048 rows)
    gemm256_kernel<1><<<dim3(NROWS / 256, 8), 512, 0, stream>>>(
        hs_bf, WqT, bq, bk, nullptr, nullptr, q_bf, k_bf, WqaT, qraw);

    // fused: softmax(qraw) -> pool q -> qkscore -> softmax -> pool k
    attnmid_kernel<<<BB * HH, 512, 0, stream>>>(qraw, bqa, mask, q_bf, k_bf, pk);

    wtscale_kernel<<<4096, 256, 0, stream>>>(WtT, pk, WtT8);

    // out = q_bf @ (pk-scaled Wt)^T + bt + q_bf   (res == A, shared fetch)
    gemm256_kernel<2><<<dim3(NROWS / 256, 4), 512, 0, stream>>>(
        q_bf, WtT8, bt, nullptr, q_bf, out, nullptr, nullptr, nullptr, nullptr);
}

// Round 7
// 275.237 us; speedup vs baseline: 1.2119x; 1.0357x over previous
//
#include <hip/hip_runtime.h>
#include <hip/hip_bf16.h>
#include <math.h>

#define BB 8
#define SS 2048
#define DD 1024
#define HH 16
#define DHH 64
#define NROWS (BB*SS)   // 16384
#define QSLICE ((size_t)BB * HH * SS)   // elems per qscore K-split slice

typedef unsigned short u16;
typedef __attribute__((ext_vector_type(8))) __bf16 bf16x8;
typedef __attribute__((ext_vector_type(4))) float f32x4;

__device__ __forceinline__ u16 f2bf(float f) {
    union { float f; unsigned u; } v; v.f = f;
    unsigned r = v.u + 0x7fffu + ((v.u >> 16) & 1u);
    return (u16)(r >> 16);
}
__device__ __forceinline__ float bf2f(u16 b) {
    union { unsigned u; float f; } v; v.u = ((unsigned)b) << 16;
    return v.f;
}

__device__ __forceinline__ void load_lds16(const void* g, void* l) {
    __builtin_amdgcn_global_load_lds(
        (const __attribute__((address_space(1))) unsigned int*)g,
        (__attribute__((address_space(3))) unsigned int*)l,
        16, 0, 0);
}

// raw workgroup barrier WITHOUT the vmcnt(0)/lgkmcnt(0) drain __syncthreads forces.
#define BAR() do { asm volatile("" ::: "memory"); \
                   __builtin_amdgcn_s_barrier();  \
                   asm volatile("" ::: "memory"); } while (0)

// ---------------- merged prep: cast + 3 weight transposes + wqa ----------------
__global__ __launch_bounds__(256)
void prep_kernel(const float* __restrict__ hs, u16* __restrict__ hs_bf,
                 const float* __restrict__ Wq, u16* __restrict__ WqT,
                 const float* __restrict__ Wk, u16* __restrict__ WkT,
                 const float* __restrict__ Wt, u16* __restrict__ WtT,
                 const float* __restrict__ Wqa, u16* __restrict__ WqaT) {
    __shared__ float tile[32][33];
    const int bid = blockIdx.x;
    const int t = threadIdx.x;
    if (bid < 16384) {
        int i = bid * 256 + t;
        float4 v = ((const float4*)hs)[i];
        ushort4 o;
        o.x = f2bf(v.x); o.y = f2bf(v.y); o.z = f2bf(v.z); o.w = f2bf(v.w);
        ((ushort4*)hs_bf)[i] = o;
        return;
    }
    if (bid < 19456) {
        int rel = bid - 16384;
        const float* W; u16* WT;
        if (rel < 1024)      { W = Wq; WT = WqT; }
        else if (rel < 2048) { W = Wk; WT = WkT; rel -= 1024; }
        else                 { W = Wt; WT = WtT; rel -= 2048; }
        int m0 = (rel & 31) * 32, k0 = (rel >> 5) * 32;
        int tx = t & 31, ty = t >> 5;
        #pragma unroll
        for (int i = 0; i < 4; i++) {
            int kk = ty + i * 8;
            tile[kk][tx] = W[(k0 + kk) * DD + m0 + tx];
        }
        __syncthreads();
        #pragma unroll
        for (int i = 0; i < 4; i++) {
            int mm = ty + i * 8;
            WT[(m0 + mm) * DD + k0 + tx] = f2bf(tile[tx][mm]);
        }
        return;
    }
    {
        int i = (bid - 19456) * 256 + t;
        int h = i >> 10, k = i & 1023;
        WqaT[i] = f2bf(Wqa[k * HH + h]);
    }
}

// ---------------- bf16 MFMA GEMM, 256x256 tile, BK=64, 8-phase schedule ----------------
// (unchanged — known-good)
template<int MODE>
__global__ __launch_bounds__(512, 2)
void gemm256_kernel(const u16* __restrict__ A, const u16* __restrict__ BT,
                    const float* __restrict__ b0, const float* __restrict__ b1,
                    const u16* __restrict__ res, float* __restrict__ Cf,
                    u16* __restrict__ C0, u16* __restrict__ C1,
                    const u16* __restrict__ WqaT, float* __restrict__ qraw) {
    __shared__ u16 smem[69632];
    const int by = blockIdx.y;
    const int row0 = blockIdx.x * 256;
    const int bcol0 = by * 256;
    const int colg0 = (MODE == 1) ? (bcol0 & 1023) : bcol0;
    const float* bias = (MODE == 1 && by >= 4) ? b1 : b0;
    u16* Cb = (MODE == 1 && by >= 4) ? C1 : C0;
    const u16* BTb = (MODE == 2) ? BT + ((size_t)(row0 >> 11) << 20) : BT;

    const int t = threadIdx.x;
    const int w = t >> 6, lane = t & 63;
    const int wm = w >> 2, wn = w & 3;
    const int m16 = lane & 15, quad = lane >> 4;

    f32x4 acc[8][4];
    #pragma unroll
    for (int i = 0; i < 8; i++)
        #pragma unroll
        for (int j = 0; j < 4; j++)
            acc[i][j] = (f32x4){0.f, 0.f, 0.f, 0.f};

    const int srow = t >> 3;
    const int scol = ((t & 7) ^ (srow & 7)) * 8;
    const u16* Ag = A + (size_t)(row0 + srow) * DD + scol;
    const u16* Bg = BTb + (size_t)(bcol0 + srow) * DD + scol;

    auto STAGE_H = [&](int ktile, int mat, int half) {
        if (ktile >= 16) return;
        const int buf = ktile & 1;
        const int k0 = ktile * 64;
        const u16* g = mat ? Bg : Ag;
        u16* s = smem + mat * 32768 + buf * 16384;
        #pragma unroll
        for (int j = 0; j < 2; ++j)
            load_lds16(g + k0 + (size_t)(half * 128 + j * 64) * DD,
                       s + half * 8192 + j * 4096 + t * 8);
    };

    STAGE_H(0, 0, 0); STAGE_H(0, 0, 1); STAGE_H(0, 1, 0); STAGE_H(0, 1, 1);
    STAGE_H(1, 0, 0);
    asm volatile("s_waitcnt vmcnt(2)" ::: "memory");
    BAR();

    for (int kt = 0; kt < 16; ++kt) {
        const int cur = kt & 1;
        const u16* sAc = smem + cur * 16384;
        const u16* sBc = smem + 32768 + cur * 16384;
        bf16x8 af[4][2], bfr[4][2];

        #pragma unroll
        for (int mi = 0; mi < 4; ++mi)
            #pragma unroll
            for (int ks = 0; ks < 2; ++ks)
                af[mi][ks] = *(const bf16x8*)&sAc[(wm * 128 + mi * 16 + m16) * 64 +
                                                 (((ks * 4 + quad) ^ (m16 & 7)) * 8)];
        #pragma unroll
        for (int ni = 0; ni < 2; ++ni)
            #pragma unroll
            for (int ks = 0; ks < 2; ++ks)
                bfr[ni][ks] = *(const bf16x8*)&sBc[(wn * 64 + ni * 16 + m16) * 64 +
                                                   (((ks * 4 + quad) ^ (m16 & 7)) * 8)];
        STAGE_H(kt + 1, 0, 1);
        BAR();
        __builtin_amdgcn_s_setprio(1);
        #pragma unroll
        for (int mi = 0; mi < 4; ++mi)
            #pragma unroll
            for (int ni = 0; ni < 2; ++ni)
                #pragma unroll
                for (int ks = 0; ks < 2; ++ks)
                    acc[mi][ni] = __builtin_amdgcn_mfma_f32_16x16x32_bf16(
                        bfr[ni][ks], af[mi][ks], acc[mi][ni], 0, 0, 0);
        __builtin_amdgcn_s_setprio(0);
        BAR();

        #pragma unroll
        for (int ni = 2; ni < 4; ++ni)
            #pragma unroll
            for (int ks = 0; ks < 2; ++ks)
                bfr[ni][ks] = *(const bf16x8*)&sBc[(wn * 64 + ni * 16 + m16) * 64 +
                                                   (((ks * 4 + quad) ^ (m16 & 7)) * 8)];
        STAGE_H(kt + 1, 1, 0);
        BAR();
        __builtin_amdgcn_s_setprio(1);
        #pragma unroll
        for (int mi = 0; mi < 4; ++mi)
            #pragma unroll
            for (int ni = 2; ni < 4; ++ni)
                #pragma unroll
                for (int ks = 0; ks < 2; ++ks)
                    acc[mi][ni] = __builtin_amdgcn_mfma_f32_16x16x32_bf16(
                        bfr[ni][ks], af[mi][ks], acc[mi][ni], 0, 0, 0);
        __builtin_amdgcn_s_setprio(0);
        BAR();

        #pragma unroll
        for (int mi = 0; mi < 4; ++mi)
            #pragma unroll
            for (int ks = 0; ks < 2; ++ks)
                af[mi][ks] = *(const bf16x8*)&sAc[(wm * 128 + (4 + mi) * 16 + m16) * 64 +
                                                 (((ks * 4 + quad) ^ (m16 & 7)) * 8)];
        STAGE_H(kt + 1, 1, 1);
        BAR();
        __builtin_amdgcn_s_setprio(1);
        #pragma unroll
        for (int mi = 0; mi < 4; ++mi)
            #pragma unroll
            for (int ni = 0; ni < 2; ++ni)
                #pragma unroll
                for (int ks = 0; ks < 2; ++ks)
                    acc[4 + mi][ni] = __builtin_amdgcn_mfma_f32_16x16x32_bf16(
                        bfr[ni][ks], af[mi][ks], acc[4 + mi][ni], 0, 0, 0);
        __builtin_amdgcn_s_setprio(0);
        BAR();

        STAGE_H(kt + 2, 0, 0);
        BAR();
        __builtin_amdgcn_s_setprio(1);
        #pragma unroll
        for (int mi = 0; mi < 4; ++mi)
            #pragma unroll
            for (int ni = 2; ni < 4; ++ni)
                #pragma unroll
                for (int ks = 0; ks < 2; ++ks)
                    acc[4 + mi][ni] = __builtin_amdgcn_mfma_f32_16x16x32_bf16(
                        bfr[ni][ks], af[mi][ks], acc[4 + mi][ni], 0, 0, 0);
        __builtin_amdgcn_s_setprio(0);
        if (kt < 14) asm volatile("s_waitcnt vmcnt(2)" ::: "memory");
        else         asm volatile("s_waitcnt vmcnt(0)" ::: "memory");
        BAR();
    }

    u16* sC = smem;
    #pragma unroll
    for (int mi = 0; mi < 8; ++mi) {
        const int lrow = wm * 128 + mi * 16 + m16;
        #pragma unroll
        for (int ni = 0; ni < 4; ++ni) {
            const int lcol = wn * 64 + ni * 16 + quad * 4;
            const float4 bv = *(const float4*)&bias[colg0 + lcol];
            if (MODE == 1) {
                ushort4 o;
                o.x = f2bf(acc[mi][ni][0] + bv.x);
                o.y = f2bf(acc[mi][ni][1] + bv.y);
                o.z = f2bf(acc[mi][ni][2] + bv.z);
                o.w = f2bf(acc[mi][ni][3] + bv.w);
                *(ushort4*)&sC[(size_t)lrow * 272 + lcol] = o;
            } else {
                const size_t idx = (size_t)(row0 + lrow) * DD + colg0 + lcol;
                const ushort4 rv = *(const ushort4*)&res[idx];
                float4 o;
                o.x = acc[mi][ni][0] + bv.x + bf2f(rv.x);
                o.y = acc[mi][ni][1] + bv.y + bf2f(rv.y);
                o.z = acc[mi][ni][2] + bv.z + bf2f(rv.z);
                o.w = acc[mi][ni][3] + bv.w + bf2f(rv.w);
                *(float4*)&Cf[idx] = o;
            }
        }
    }
    if (MODE == 1) {
        __syncthreads();
        #pragma unroll
        for (int it = 0; it < 16; ++it) {
            const int r = it * 16 + (t >> 5);
            const int c = t & 31;
            uint4 v = *(const uint4*)&sC[(size_t)r * 272 + c * 8];
            *(uint4*)&Cb[(size_t)(row0 + r) * DD + colg0 + c * 8] = v;
        }
        if (by < 4) {
            const int bIdx = row0 >> 11;
            bf16x8 wq[8];
            const u16* bp = WqaT + (size_t)m16 * DD + by * 256 + quad * 8;
            #pragma unroll
            for (int kk = 0; kk < 8; ++kk) wq[kk] = *(const bf16x8*)(bp + kk * 32);
            #pragma unroll
            for (int rt = 0; rt < 2; ++rt) {
                const int sr = (w * 2 + rt) * 16;
                f32x4 qa = (f32x4){0.f, 0.f, 0.f, 0.f};
                #pragma unroll
                for (int kk = 0; kk < 8; ++kk) {
                    bf16x8 a = *(const bf16x8*)&sC[(size_t)(sr + m16) * 272 + quad * 8 + kk * 32];
                    qa = __builtin_amdgcn_mfma_f32_16x16x32_bf16(a, wq[kk], qa, 0, 0, 0);
                }
                #pragma unroll
                for (int r = 0; r < 4; ++r) {
                    int s = (row0 & 2047) + sr + quad * 4 + r;
                    qraw[((size_t)(by * BB + bIdx) * HH + m16) * SS + s] = qa[r];
                }
            }
        }
    }
}

// ---------------- fused middle v2: 1024 threads, vectorized, shuffle-reduced ------
// one block per (b,h), 16 waves. All pool/score loads are uint4 (16B/lane),
// wave covers 8 rows x 128B contiguous per instruction. No atomics.
__global__ __launch_bounds__(1024)
void attnmid_kernel(const float* __restrict__ qraw, const float* __restrict__ bqa,
                    const float* __restrict__ mask, const u16* __restrict__ qbf,
                    const u16* __restrict__ kbf, float* __restrict__ pk) {
    const int bh = blockIdx.x;
    const int b = bh >> 4, h = bh & 15;
    const int t = threadIdx.x;
    const int wid = t >> 6, lane = t & 63;
    const int sub = lane & 7;        // dim group: dims [sub*8, sub*8+8)
    const int srw = lane >> 3;       // row-within-wave 0..7

    __shared__ float sw[SS];         // row weights / raw scores (8 KB)
    __shared__ float redM[16], redS[16];
    __shared__ float prr[16][64];    // per-wave pool partials
    __shared__ float pql[64];        // pooled_q

    // ---- phase 1: softmax of q attention logits (from 4 K-split slices) ----
    {
        const float* qr = qraw + ((size_t)bh << 11);
        const float bq_ = bqa[h];
        float x0 = qr[t] + qr[t + QSLICE] + qr[t + 2 * QSLICE] + qr[t + 3 * QSLICE];
        float x1 = qr[t + 1024] + qr[t + 1024 + QSLICE] + qr[t + 1024 + 2 * QSLICE]
                 + qr[t + 1024 + 3 * QSLICE];
        x0 = (x0 + bq_) * 0.125f + mask[b * SS + t];
        x1 = (x1 + bq_) * 0.125f + mask[b * SS + t + 1024];
        float m = fmaxf(x0, x1);
        #pragma unroll
        for (int o = 32; o; o >>= 1) m = fmaxf(m, __shfl_xor(m, o));
        if (lane == 0) redM[wid] = m;
        __syncthreads();
        m = redM[0];
        #pragma unroll
        for (int i = 1; i < 16; i++) m = fmaxf(m, redM[i]);
        float e0 = __expf(x0 - m), e1 = __expf(x1 - m);
        float sum = e0 + e1;
        #pragma unroll
        for (int o = 32; o; o >>= 1) sum += __shfl_xor(sum, o);
        if (lane == 0) redS[wid] = sum;
        __syncthreads();
        float tot = 0.f;
        #pragma unroll
        for (int i = 0; i < 16; i++) tot += redS[i];
        float inv = 1.0f / tot;
        sw[t] = e0 * inv;
        sw[t + 1024] = e1 * inv;
        __syncthreads();
    }

    // ---- phase 2: pool q -> pql[64] ----
    {
        const u16* qb = qbf + (((size_t)b * SS) << 10) + h * 64 + sub * 8;
        float a[8];
        #pragma unroll
        for (int j = 0; j < 8; j++) a[j] = 0.f;
        #pragma unroll
        for (int it = 0; it < 16; ++it) {
            int s = it * 128 + wid * 8 + srw;
            uint4 kv = *(const uint4*)(qb + ((size_t)s << 10));
            float wf = sw[s];
            unsigned ww[4] = {kv.x, kv.y, kv.z, kv.w};
            #pragma unroll
            for (int j = 0; j < 4; j++) {
                union { unsigned u; float f; } lo, hi;
                lo.u = ww[j] << 16; hi.u = ww[j] & 0xffff0000u;
                a[2 * j]     += wf * lo.f;
                a[2 * j + 1] += wf * hi.f;
            }
        }
        #pragma unroll
        for (int o = 8; o <= 32; o <<= 1)
            #pragma unroll
            for (int j = 0; j < 8; j++) a[j] += __shfl_xor(a[j], o);
        if (srw == 0)
            #pragma unroll
            for (int j = 0; j < 8; j++) prr[wid][sub * 8 + j] = a[j];
        __syncthreads();
        if (t < 64) {
            float s2 = 0.f;
            #pragma unroll
            for (int w2 = 0; w2 < 16; w2++) s2 += prr[w2][t];
            pql[t] = s2;
        }
        __syncthreads();
    }

    // ---- phase 3: raw qk scores (s-major, coalesced), then softmax ----
    {
        const u16* kb = kbf + (((size_t)b * SS) << 10) + h * 64 + sub * 8;
        float pqr[8];
        #pragma unroll
        for (int j = 0; j < 8; j++) pqr[j] = pql[sub * 8 + j];
        #pragma unroll
        for (int it = 0; it < 16; ++it) {
            int s = it * 128 + wid * 8 + srw;
            uint4 kv = *(const uint4*)(kb + ((size_t)s << 10));
            unsigned ww[4] = {kv.x, kv.y, kv.z, kv.w};
            float d = 0.f;
            #pragma unroll
            for (int j = 0; j < 4; j++) {
                union { unsigned u; float f; } lo, hi;
                lo.u = ww[j] << 16; hi.u = ww[j] & 0xffff0000u;
                d += lo.f * pqr[2 * j] + hi.f * pqr[2 * j + 1];
            }
            d += __shfl_xor(d, 1);
            d += __shfl_xor(d, 2);
            d += __shfl_xor(d, 4);
            if (sub == 0) sw[s] = d * 0.125f + mask[b * SS + s];
        }
        __syncthreads();
        // softmax over sw
        float x0 = sw[t], x1 = sw[t + 1024];
        float m = fmaxf(x0, x1);
        #pragma unroll
        for (int o = 32; o; o >>= 1) m = fmaxf(m, __shfl_xor(m, o));
        if (lane == 0) redM[wid] = m;
        __syncthreads();
        m = redM[0];
        #pragma unroll
        for (int i = 1; i < 16; i++) m = fmaxf(m, redM[i]);
        float e0 = __expf(x0 - m), e1 = __expf(x1 - m);
        float sum = e0 + e1;
        #pragma unroll
        for (int o = 32; o; o >>= 1) sum += __shfl_xor(sum, o);
        if (lane == 0) redS[wid] = sum;
        __syncthreads();
        float tot = 0.f;
        #pragma unroll
        for (int i = 0; i < 16; i++) tot += redS[i];
        float inv = 1.0f / tot;
        sw[t] = e0 * inv;
        sw[t + 1024] = e1 * inv;
        __syncthreads();
    }

    // ---- phase 4: pool k -> pk[b, h*64 + d] ----
    {
        const u16* kb = kbf + (((size_t)b * SS) << 10) + h * 64 + sub * 8;
        float a[8];
        #pragma unroll
        for (int j = 0; j < 8; j++) a[j] = 0.f;
        #pragma unroll
        for (int it = 0; it < 16; ++it) {
            int s = it * 128 + wid * 8 + srw;
            uint4 kv = *(const uint4*)(kb + ((size_t)s << 10));
            float wf = sw[s];
            unsigned ww[4] = {kv.x, kv.y, kv.z, kv.w};
            #pragma unroll
            for (int j = 0; j < 4; j++) {
                union { unsigned u; float f; } lo, hi;
                lo.u = ww[j] << 16; hi.u = ww[j] & 0xffff0000u;
                a[2 * j]     += wf * lo.f;
                a[2 * j + 1] += wf * hi.f;
            }
        }
        #pragma unroll
        for (int o = 8; o <= 32; o <<= 1)
            #pragma unroll
            for (int j = 0; j < 8; j++) a[j] += __shfl_xor(a[j], o);
        if (srw == 0)
            #pragma unroll
            for (int j = 0; j < 8; j++) prr[wid][sub * 8 + j] = a[j];
        __syncthreads();
        if (t < 64) {
            float s2 = 0.f;
            #pragma unroll
            for (int w2 = 0; w2 < 16; w2++) s2 += prr[w2][t];
            pk[b * DD + h * 64 + t] = s2;
        }
    }
}

// ---------------- WtT8[b][n][k] = bf16( WtT[n][k] * pk[b][k] ) ----------------
__global__ __launch_bounds__(256)
void wtscale_kernel(const u16* __restrict__ WtT, const float* __restrict__ pk,
                    u16* __restrict__ WtT8) {
    size_t i = (size_t)blockIdx.x * 256 + threadIdx.x;   // < 1048576
    int b = (int)(i >> 17);
    size_t off = (i & 131071) << 3;
    int d = (int)(off & 1023);
    const float4 p0 = *(const float4*)&pk[b * 1024 + d];
    const float4 p1 = *(const float4*)&pk[b * 1024 + d + 4];
    ushort4 a0 = ((const ushort4*)(WtT + off))[0];
    ushort4 a1 = ((const ushort4*)(WtT + off))[1];
    ushort4 o0, o1;
    o0.x = f2bf(bf2f(a0.x) * p0.x); o0.y = f2bf(bf2f(a0.y) * p0.y);
    o0.z = f2bf(bf2f(a0.z) * p0.z); o0.w = f2bf(bf2f(a0.w) * p0.w);
    o1.x = f2bf(bf2f(a1.x) * p1.x); o1.y = f2bf(bf2f(a1.y) * p1.y);
    o1.z = f2bf(bf2f(a1.z) * p1.z); o1.w = f2bf(bf2f(a1.w) * p1.w);
    u16* dst = WtT8 + ((size_t)b << 20) + off;
    ((ushort4*)dst)[0] = o0;
    ((ushort4*)dst)[1] = o1;
}

extern "C" void kernel_launch(void* const* d_in, const int* in_sizes, int n_in,
                              void* d_out, int out_size, void* d_ws, size_t ws_size,
                              hipStream_t stream) {
    const float* hs   = (const float*)d_in[0];
    const float* mask = (const float*)d_in[1];
    const float* Wq   = (const float*)d_in[2];
    const float* bq   = (const float*)d_in[3];
    const float* Wqa  = (const float*)d_in[4];
    const float* bqa  = (const float*)d_in[5];
    const float* Wk   = (const float*)d_in[6];
    const float* bk   = (const float*)d_in[7];
    const float* Wt   = (const float*)d_in[8];
    const float* bt   = (const float*)d_in[9];
    float* out = (float*)d_out;

    char* ws = (char*)d_ws;
    u16*   hs_bf = (u16*)ws;   ws += (size_t)NROWS * DD * 2;
    u16*   WqT   = (u16*)ws;   ws += (size_t)DD * DD * 2;
    u16*   WkT   = (u16*)ws;   ws += (size_t)DD * DD * 2;   // adjacent to WqT (merged GEMM)
    u16*   WtT   = (u16*)ws;   ws += (size_t)DD * DD * 2;
    u16*   WqaT  = (u16*)ws;   ws += (size_t)HH * DD * 2;
    u16*   q_bf  = (u16*)ws;   ws += (size_t)NROWS * DD * 2;
    u16*   k_bf  = (u16*)ws;   ws += (size_t)NROWS * DD * 2;
    float* qraw  = (float*)ws; ws += QSLICE * 4 * 4;
    float* pk    = (float*)ws; ws += (size_t)BB * HH * 64 * 4;
    u16*   WtT8  = hs_bf;  // alias: hs_bf dead after merged QK gemm

    prep_kernel<<<19520, 256, 0, stream>>>(hs, hs_bf, Wq, WqT, Wk, WkT, Wt, WtT,
                                           Wqa, WqaT);

    gemm256_kernel<1><<<dim3(NROWS / 256, 8), 512, 0, stream>>>(
        hs_bf, WqT, bq, bk, nullptr, nullptr, q_bf, k_bf, WqaT, qraw);

    attnmid_kernel<<<BB * HH, 1024, 0, stream>>>(qraw, bqa, mask, q_bf, k_bf, pk);

    wtscale_kernel<<<4096, 256, 0, stream>>>(WtT, pk, WtT8);

    gemm256_kernel<2><<<dim3(NROWS / 256, 4), 512, 0, stream>>>(
        q_bf, WtT8, bt, nullptr, q_bf, out, nullptr, nullptr, nullptr, nullptr);
}